// Round 2
// baseline (466.270 us; speedup 1.0000x reference)
//
#include <hip/hip_runtime.h>
#include <math.h>

#define IC 64
#define OC 16
#define DIM 64

// ---------------------------------------------------------------------------
// kSetup: weight transposes + beta folding.
//  WF2t[h][m][d] = W_F2[m][h][d]                       (65536)
//  WSt2[m][fo][i][fi] = W_S[i][m][fo*4+fi]             (65536, lane-i coalesced x4)
//  BSt[m][i] = B_S[i][m]; cb[i][m]=bu+bi; db[i]=sum_m bi; eb[i]=sum_m cb/16 - db
// ---------------------------------------------------------------------------
__global__ void kSetup(const float* __restrict__ W_F2, const float* __restrict__ W_S,
                       const float* __restrict__ B_S, const float* __restrict__ bu,
                       const float* __restrict__ bi_,
                       float* __restrict__ WF2t, float* __restrict__ WSt2,
                       float* __restrict__ BSt, float* __restrict__ cb,
                       float* __restrict__ db, float* __restrict__ eb)
{
    int e = blockIdx.x * 256 + threadIdx.x; // 0..65535
    {
        int h = e >> 10, m = (e >> 6) & 15, d = e & 63;
        WF2t[e] = W_F2[((size_t)m * 64 + h) * 64 + d];
    }
    {
        int m = e >> 12, fo = (e >> 8) & 15, i = (e >> 2) & 63, fi = e & 3;
        WSt2[e] = W_S[((size_t)i * 16 + m) * 64 + fo * 4 + fi];
    }
    if (e < 1024) {
        int m = e >> 6, i = e & 63;
        BSt[e] = B_S[i * 16 + m];
        cb[e] = bu[e] + bi_[e]; // [i][m] layout (input layout)
    }
    if (e < 64) {
        float sc = 0.f, sd = 0.f;
        for (int m = 0; m < 16; m++) {
            sc += bu[e * 16 + m] + bi_[e * 16 + m];
            sd += bi_[e * 16 + m];
        }
        db[e] = sd;
        eb[e] = sc * (1.0f / 16.0f) - sd;
    }
}

// ---------------------------------------------------------------------------
// kA: tF[b][i][h] = (x[b][i][:] @ W_F1[i]) * 0.125
//     fa[b][i]    = sigmoid(dot(x[b][i][:], W_A[i])*0.125 + B_A[i])
//     phi[b][i]   = fa * eb[i]   (iteration-0 phi, uniform R)
// grid (64 b-tiles, 64 i), block 256. Both GEMM operands b128 from LDS.
// ---------------------------------------------------------------------------
__global__ __launch_bounds__(256, 4)
void kA(const float* __restrict__ x, const float* __restrict__ W_F1,
        const float* __restrict__ W_A, const float* __restrict__ B_A,
        const float* __restrict__ eb,
        float* __restrict__ tF, float* __restrict__ fa, float* __restrict__ phi)
{
    __shared__ float XT[64][68]; // XT[f][b]
    __shared__ float Ws[64][68]; // Ws[f][h]
    __shared__ float WAs[64];
    const int i = blockIdx.y;
    const int b0 = blockIdx.x * 64;
    const int t = threadIdx.x;
    const int bl = t >> 2, c0 = (t & 3) * 16;

    { // stage x transposed + W_F1[i] natural
        const float* src = x + ((size_t)(b0 + bl) * IC + i) * DIM + c0;
#pragma unroll
        for (int j4 = 0; j4 < 4; j4++) {
            float4 v = ((const float4*)src)[j4];
            XT[c0 + j4 * 4 + 0][bl] = v.x;
            XT[c0 + j4 * 4 + 1][bl] = v.y;
            XT[c0 + j4 * 4 + 2][bl] = v.z;
            XT[c0 + j4 * 4 + 3][bl] = v.w;
        }
        const float* wsrc = W_F1 + ((size_t)i * DIM + bl) * DIM + c0;
#pragma unroll
        for (int j4 = 0; j4 < 4; j4++)
            ((float4*)&Ws[bl][c0])[j4] = ((const float4*)wsrc)[j4];
    }
    if (t < 64) WAs[t] = W_A[i * 64 + t];
    __syncthreads();

    const int tr = t >> 4, tc = t & 15;
    float acc[4][4];
#pragma unroll
    for (int r = 0; r < 4; r++)
#pragma unroll
        for (int c = 0; c < 4; c++) acc[r][c] = 0.f;

#pragma unroll 8
    for (int k = 0; k < 64; k++) {
        float4 a = *(const float4*)&XT[k][tr * 4];
        float4 w = *(const float4*)&Ws[k][tc * 4];
        float ar[4] = {a.x, a.y, a.z, a.w};
#pragma unroll
        for (int r = 0; r < 4; r++) {
            acc[r][0] += ar[r] * w.x; acc[r][1] += ar[r] * w.y;
            acc[r][2] += ar[r] * w.z; acc[r][3] += ar[r] * w.w;
        }
    }
#pragma unroll
    for (int r = 0; r < 4; r++) {
        float4 o;
        o.x = acc[r][0] * 0.125f; o.y = acc[r][1] * 0.125f;
        o.z = acc[r][2] * 0.125f; o.w = acc[r][3] * 0.125f;
        *(float4*)&tF[((size_t)(b0 + tr * 4 + r) * IC + i) * DIM + tc * 4] = o;
    }
    if (t < 64) { // fa + phi0 for b = b0+t
        float a = 0.f;
        for (int f = 0; f < 64; f++) a += XT[f][t] * WAs[f];
        float ae = a * 0.125f + B_A[i];
        float fv = 1.0f / (1.0f + expf(-ae));
        fa[(size_t)(b0 + t) * IC + i] = fv;
        phi[(size_t)(b0 + t) * IC + i] = fv * eb[i];
    }
}

// ---------------------------------------------------------------------------
// kS: s[b][h] = sum_i phi[b][i] * tF[b][i][h].  grid 1024 (4 b / block).
// ---------------------------------------------------------------------------
__global__ __launch_bounds__(256, 4)
void kS(const float* __restrict__ phi, const float* __restrict__ tF,
        float* __restrict__ s)
{
    __shared__ float ph[4 * 64];
    const int b0 = blockIdx.x * 4;
    const int t = threadIdx.x;
    ph[t] = phi[(size_t)b0 * IC + t];
    __syncthreads();
    const int g = t >> 6, h = t & 63;
    const float* tfp = tF + ((size_t)(b0 + g) * IC) * DIM + h;
    float a = 0.f;
#pragma unroll 8
    for (int i = 0; i < IC; i++)
        a += ph[g * 64 + i] * tfp[(size_t)i * DIM];
    s[(size_t)(b0 + g) * DIM + h] = a;
}

// ---------------------------------------------------------------------------
// kXG: per (b-tile 64, m): three chained 64x64x64 GEMMs out of LDS.
//  GEMM1: x_out = s @ W_F2t[:,m,:] + B_F2[m]   -> (last: write out, exit)
//  LN (in-register, shfl over the 16-lane row group)
//  GEMM2: tG = xnorm @ W_G1
//  GEMM3: xhat = tG @ W_G2[m] + B_G2[m]  -> write xhat[b][m][f]
// ---------------------------------------------------------------------------
__global__ __launch_bounds__(256, 4)
void kXG(const float* __restrict__ s, const float* __restrict__ WF2t,
         const float* __restrict__ B_F2, const float* __restrict__ W_G1,
         const float* __restrict__ W_G2, const float* __restrict__ B_G2,
         const float* __restrict__ gam, const float* __restrict__ bet,
         float* __restrict__ xhat, float* __restrict__ out, const int last)
{
    __shared__ float A[64][68];  // sT -> xnT -> tGT  (A[k][b])
    __shared__ float Wb[64][68]; // W panel [k][col]
    const int b0 = blockIdx.x * 64;
    const int m = blockIdx.y;
    const int t = threadIdx.x;
    const int bl = t >> 2, c0 = (t & 3) * 16;
    const int tr = t >> 4, tc = t & 15;

    { // stage sT + W_F2t panel for m
        const float* src = s + (size_t)(b0 + bl) * DIM + c0;
#pragma unroll
        for (int j4 = 0; j4 < 4; j4++) {
            float4 v = ((const float4*)src)[j4];
            A[c0 + j4 * 4 + 0][bl] = v.x;
            A[c0 + j4 * 4 + 1][bl] = v.y;
            A[c0 + j4 * 4 + 2][bl] = v.z;
            A[c0 + j4 * 4 + 3][bl] = v.w;
        }
        const float* wsrc = WF2t + ((size_t)bl * OC + m) * DIM + c0;
#pragma unroll
        for (int j4 = 0; j4 < 4; j4++)
            ((float4*)&Wb[bl][c0])[j4] = ((const float4*)wsrc)[j4];
    }
    __syncthreads();

    float acc[4][4];
#pragma unroll
    for (int r = 0; r < 4; r++)
#pragma unroll
        for (int c = 0; c < 4; c++) acc[r][c] = 0.f;
#pragma unroll 8
    for (int k = 0; k < 64; k++) {
        float4 a = *(const float4*)&A[k][tr * 4];
        float4 w = *(const float4*)&Wb[k][tc * 4];
        float ar[4] = {a.x, a.y, a.z, a.w};
#pragma unroll
        for (int r = 0; r < 4; r++) {
            acc[r][0] += ar[r] * w.x; acc[r][1] += ar[r] * w.y;
            acc[r][2] += ar[r] * w.z; acc[r][3] += ar[r] * w.w;
        }
    }
    { // + B_F2[m]
        float4 bf = *(const float4*)&B_F2[m * DIM + tc * 4];
#pragma unroll
        for (int r = 0; r < 4; r++) {
            acc[r][0] += bf.x; acc[r][1] += bf.y;
            acc[r][2] += bf.z; acc[r][3] += bf.w;
        }
    }
    if (last) { // final x_out, done
#pragma unroll
        for (int r = 0; r < 4; r++)
            *(float4*)&out[((size_t)(b0 + tr * 4 + r) * OC + m) * DIM + tc * 4] =
                make_float4(acc[r][0], acc[r][1], acc[r][2], acc[r][3]);
        return;
    }
    { // LayerNorm rows (row = b, spread over 16 lanes sharing tr)
        float4 gv = *(const float4*)&gam[tc * 4];
        float4 bv = *(const float4*)&bet[tc * 4];
#pragma unroll
        for (int r = 0; r < 4; r++) {
            float sum = acc[r][0] + acc[r][1] + acc[r][2] + acc[r][3];
            float sq = acc[r][0] * acc[r][0] + acc[r][1] * acc[r][1] +
                       acc[r][2] * acc[r][2] + acc[r][3] * acc[r][3];
#pragma unroll
            for (int k = 1; k <= 8; k <<= 1) {
                sum += __shfl_xor(sum, k);
                sq  += __shfl_xor(sq, k);
            }
            float mu = sum * (1.0f / 64.0f);
            float var = sq * (1.0f / 64.0f) - mu * mu;
            float rs = 1.0f / sqrtf(var + 1e-5f);
            acc[r][0] = (acc[r][0] - mu) * rs * gv.x + bv.x;
            acc[r][1] = (acc[r][1] - mu) * rs * gv.y + bv.y;
            acc[r][2] = (acc[r][2] - mu) * rs * gv.z + bv.z;
            acc[r][3] = (acc[r][3] - mu) * rs * gv.w + bv.w;
        }
    }
    __syncthreads(); // GEMM1 reads of A/Wb complete
    { // A <- xnorm^T ; Wb <- W_G1
#pragma unroll
        for (int r = 0; r < 4; r++)
#pragma unroll
            for (int c = 0; c < 4; c++)
                A[tc * 4 + c][tr * 4 + r] = acc[r][c];
        const float* wsrc = W_G1 + (size_t)bl * DIM + c0;
#pragma unroll
        for (int j4 = 0; j4 < 4; j4++)
            ((float4*)&Wb[bl][c0])[j4] = ((const float4*)wsrc)[j4];
    }
    __syncthreads();

    float tg[4][4];
#pragma unroll
    for (int r = 0; r < 4; r++)
#pragma unroll
        for (int c = 0; c < 4; c++) tg[r][c] = 0.f;
#pragma unroll 8
    for (int k = 0; k < 64; k++) {
        float4 a = *(const float4*)&A[k][tr * 4];
        float4 w = *(const float4*)&Wb[k][tc * 4];
        float ar[4] = {a.x, a.y, a.z, a.w};
#pragma unroll
        for (int r = 0; r < 4; r++) {
            tg[r][0] += ar[r] * w.x; tg[r][1] += ar[r] * w.y;
            tg[r][2] += ar[r] * w.z; tg[r][3] += ar[r] * w.w;
        }
    }
    __syncthreads(); // GEMM2 reads complete
    { // A <- tG^T ; Wb <- W_G2[m]
#pragma unroll
        for (int r = 0; r < 4; r++)
#pragma unroll
            for (int c = 0; c < 4; c++)
                A[tc * 4 + c][tr * 4 + r] = tg[r][c];
        const float* wsrc = W_G2 + ((size_t)m * DIM + bl) * DIM + c0;
#pragma unroll
        for (int j4 = 0; j4 < 4; j4++)
            ((float4*)&Wb[bl][c0])[j4] = ((const float4*)wsrc)[j4];
    }
    __syncthreads();

    float xh[4][4];
    {
        float4 bg = *(const float4*)&B_G2[m * DIM + tc * 4];
#pragma unroll
        for (int r = 0; r < 4; r++) {
            xh[r][0] = bg.x; xh[r][1] = bg.y; xh[r][2] = bg.z; xh[r][3] = bg.w;
        }
    }
#pragma unroll 8
    for (int k = 0; k < 64; k++) {
        float4 a = *(const float4*)&A[k][tr * 4];
        float4 w = *(const float4*)&Wb[k][tc * 4];
        float ar[4] = {a.x, a.y, a.z, a.w};
#pragma unroll
        for (int r = 0; r < 4; r++) {
            xh[r][0] += ar[r] * w.x; xh[r][1] += ar[r] * w.y;
            xh[r][2] += ar[r] * w.z; xh[r][3] += ar[r] * w.w;
        }
    }
#pragma unroll
    for (int r = 0; r < 4; r++)
        *(float4*)&xhat[((size_t)(b0 + tr * 4 + r) * OC + m) * DIM + tc * 4] =
            make_float4(xh[r][0], xh[r][1], xh[r][2], xh[r][3]);
}

// ---------------------------------------------------------------------------
// kC: consistency + softmax + phi.  grid 512 (8 b / block), 256 thr.
// wave w owns m in [4w,4w+4); lane = i. xhat tile staged in LDS (broadcast reads).
// ---------------------------------------------------------------------------
__global__ __launch_bounds__(256, 2)
void kC(const float* __restrict__ x, const float* __restrict__ xhat,
        const float* __restrict__ WSt2, const float* __restrict__ BSt,
        const float* __restrict__ cb, const float* __restrict__ db,
        const float* __restrict__ fa, float* __restrict__ phi)
{
    __shared__ float buf[8704]; // xh view: (g*16+m)*64+f (8192); cons view: (g*64+i)*17+m (8704)
    const int b0 = blockIdx.x * 8;
    const int t = threadIdx.x;
    const int w = t >> 6, lane = t & 63;

    { // stage xhat[b0..b0+8) : 8192 contiguous floats
        const float4* src = (const float4*)(xhat + (size_t)b0 * OC * DIM);
        float4* dst = (float4*)buf;
#pragma unroll
        for (int j = 0; j < 8; j++) dst[t + j * 256] = src[t + j * 256];
    }
    __syncthreads();

    float acc[8][4];
#pragma unroll
    for (int k = 0; k < 4; k++) {
        float bs = BSt[(w * 4 + k) * IC + lane];
#pragma unroll
        for (int g = 0; g < 8; g++) acc[g][k] = bs;
    }

    for (int fc = 0; fc < 64; fc += 16) {
        float wreg[4][16];
#pragma unroll
        for (int k = 0; k < 4; k++) {
            int m = w * 4 + k;
#pragma unroll
            for (int q = 0; q < 4; q++) {
                float4 v = *(const float4*)&WSt2[(((size_t)m * 16 + (fc >> 2) + q) * IC + lane) * 4];
                wreg[k][q * 4 + 0] = v.x; wreg[k][q * 4 + 1] = v.y;
                wreg[k][q * 4 + 2] = v.z; wreg[k][q * 4 + 3] = v.w;
            }
        }
#pragma unroll
        for (int g = 0; g < 8; g++) {
            float xr[16];
            const float* xp = x + ((size_t)(b0 + g) * IC + lane) * DIM + fc;
#pragma unroll
            for (int q = 0; q < 4; q++) {
                float4 v = *(const float4*)(xp + q * 4);
                xr[q * 4 + 0] = v.x; xr[q * 4 + 1] = v.y;
                xr[q * 4 + 2] = v.z; xr[q * 4 + 3] = v.w;
            }
#pragma unroll
            for (int k = 0; k < 4; k++) {
                int m = w * 4 + k;
                const float* hp = &buf[(g * OC + m) * DIM + fc];
                float hr[16];
#pragma unroll
                for (int q = 0; q < 4; q++) {
                    float4 v = *(const float4*)(hp + q * 4);
                    hr[q * 4 + 0] = v.x; hr[q * 4 + 1] = v.y;
                    hr[q * 4 + 2] = v.z; hr[q * 4 + 3] = v.w;
                }
#pragma unroll
                for (int ff = 0; ff < 16; ff++)
                    acc[g][k] += xr[ff] * hr[ff] * wreg[k][ff];
            }
        }
    }
    __syncthreads(); // all xh reads done before overwrite
#pragma unroll
    for (int g = 0; g < 8; g++)
#pragma unroll
        for (int k = 0; k < 4; k++)
            buf[(g * IC + lane) * 17 + w * 4 + k] = acc[g][k];
    __syncthreads();

    // softmax over m + phi, 2 (g,i) pairs per thread
    for (int p = t; p < 512; p += 256) {
        int g = p >> 6, i = p & 63;
        const float* row = &buf[(g * IC + i) * 17];
        float v[16], mx = -1e30f;
#pragma unroll
        for (int m = 0; m < OC; m++) { v[m] = row[m]; mx = fmaxf(mx, v[m]); }
        float sum = 0.f;
#pragma unroll
        for (int m = 0; m < OC; m++) { v[m] = expf(v[m] - mx); sum += v[m]; }
        float inv = 1.0f / sum;
        float a2 = 0.f;
#pragma unroll
        for (int m = 0; m < OC; m++) a2 += v[m] * inv * cb[i * OC + m];
        size_t bi = (size_t)(b0 + g) * IC + i;
        phi[bi] = fa[bi] * (a2 - db[i]);
    }
}

// ---------------------------------------------------------------------------
extern "C" void kernel_launch(void* const* d_in, const int* in_sizes, int n_in,
                              void* d_out, int out_size, void* d_ws, size_t ws_size,
                              hipStream_t stream)
{
    const float* x    = (const float*)d_in[0];
    const float* W_A  = (const float*)d_in[1];
    const float* B_A  = (const float*)d_in[2];
    const float* W_F1 = (const float*)d_in[3];
    const float* W_F2 = (const float*)d_in[4];
    const float* B_F2 = (const float*)d_in[5];
    const float* W_G1 = (const float*)d_in[6];
    const float* W_G2 = (const float*)d_in[7];
    const float* B_G2 = (const float*)d_in[8];
    const float* gam  = (const float*)d_in[9];
    const float* bet  = (const float*)d_in[10];
    const float* W_S  = (const float*)d_in[11];
    const float* B_S  = (const float*)d_in[12];
    const float* bu   = (const float*)d_in[13];
    const float* bi_  = (const float*)d_in[14];

    float* ws   = (float*)d_ws;
    float* tF   = ws;                          // 4096*64*64 = 16777216
    float* fa   = tF + 16777216;               // 262144
    float* phi  = fa + 262144;                 // 262144
    float* s    = phi + 262144;                // 262144
    float* xhat = s + 262144;                  // 4096*16*64 = 4194304
    float* WF2t = xhat + 4194304;              // 65536
    float* WSt2 = WF2t + 65536;                // 65536
    float* BSt  = WSt2 + 65536;                // 1024
    float* cb   = BSt + 1024;                  // 1024
    float* db   = cb + 1024;                   // 64
    float* eb   = db + 64;                     // 64
    float* out  = (float*)d_out;

    kSetup<<<256, 256, 0, stream>>>(W_F2, W_S, B_S, bu, bi_, WF2t, WSt2, BSt, cb, db, eb);
    kA<<<dim3(64, 64), 256, 0, stream>>>(x, W_F1, W_A, B_A, eb, tF, fa, phi);
    for (int it = 0; it < 3; ++it) {
        kS<<<1024, 256, 0, stream>>>(phi, tF, s);
        kXG<<<dim3(64, 16), 256, 0, stream>>>(s, WF2t, B_F2, W_G1, W_G2, B_G2,
                                              gam, bet, xhat, out, it == 2 ? 1 : 0);
        if (it < 2)
            kC<<<512, 256, 0, stream>>>(x, xhat, WSt2, BSt, cb, db, fa, phi);
    }
}

// Round 3
// 391.960 us; speedup vs baseline: 1.1896x; 1.1896x over previous
//
#include <hip/hip_runtime.h>
#include <math.h>

#define IC 64
#define OC 16
#define DIM 64

// ---------------------------------------------------------------------------
// kSetup: weight transposes + beta folding.
//  WF2t[h][m][d] = W_F2[m][h][d]
//  WSt2[m][fo][i][fi] = W_S[i][m][fo*4+fi]   (lane-i coalesced float4)
//  BSt[m][i] = B_S[i][m]; cb[i][m]=bu+bi; db[i]=sum_m bi; eb[i]=sum_m cb/16 - db
// ---------------------------------------------------------------------------
__global__ void kSetup(const float* __restrict__ W_F2, const float* __restrict__ W_S,
                       const float* __restrict__ B_S, const float* __restrict__ bu,
                       const float* __restrict__ bi_,
                       float* __restrict__ WF2t, float* __restrict__ WSt2,
                       float* __restrict__ BSt, float* __restrict__ cb,
                       float* __restrict__ db, float* __restrict__ eb)
{
    int e = blockIdx.x * 256 + threadIdx.x; // 0..65535
    {
        int h = e >> 10, m = (e >> 6) & 15, d = e & 63;
        WF2t[e] = W_F2[((size_t)m * 64 + h) * 64 + d];
    }
    {
        int m = e >> 12, fo = (e >> 8) & 15, i = (e >> 2) & 63, fi = e & 3;
        WSt2[e] = W_S[((size_t)i * 16 + m) * 64 + fo * 4 + fi];
    }
    if (e < 1024) {
        int m = e >> 6, i = e & 63;
        BSt[e] = B_S[i * 16 + m];
        cb[e] = bu[e] + bi_[e];
    }
    if (e < 64) {
        float sc = 0.f, sd = 0.f;
        for (int m = 0; m < 16; m++) {
            sc += bu[e * 16 + m] + bi_[e * 16 + m];
            sd += bi_[e * 16 + m];
        }
        db[e] = sd;
        eb[e] = sc * (1.0f / 16.0f) - sd;
    }
}

// ---------------------------------------------------------------------------
// kT: fully-coalesced x pass. Produces:
//   xq[b][fo][i][fi] = x[b][i][fo*4+fi]  (f-major packed, lane-i coalesced)
//   fa[b][i] = sigmoid(dot(x[b][i][:],W_A[i])*0.125 + B_A[i]); phi0 = fa*eb[i]
// 2 batch / block, 2048 blocks. LDS rows rotated by i: elem f at (f+i)&63.
// ---------------------------------------------------------------------------
__global__ __launch_bounds__(256, 4)
void kT(const float* __restrict__ x, const float* __restrict__ W_A,
        const float* __restrict__ B_A, const float* __restrict__ eb,
        float* __restrict__ xq, float* __restrict__ fa, float* __restrict__ phi)
{
    __shared__ float Xs[2][64][64];
    const int t = threadIdx.x;
    const int blk = blockIdx.x;
    const int lane = t & 63, w = t >> 6;

    const float4* x4 = (const float4*)x;
#pragma unroll
    for (int s = 0; s < 8; s++) { // stage 2 batch rows, coalesced 1KB/instr
        int p = s * 256 + t;
        float4 v = x4[(size_t)blk * 2048 + p];
        int b = p >> 10, i = (p >> 4) & 63, fo = p & 15;
        Xs[b][i][(fo * 4 + 0 + i) & 63] = v.x;
        Xs[b][i][(fo * 4 + 1 + i) & 63] = v.y;
        Xs[b][i][(fo * 4 + 2 + i) & 63] = v.z;
        Xs[b][i][(fo * 4 + 3 + i) & 63] = v.w;
    }
    __syncthreads();

    // xq: coalesced float4 writes, lanes = i
#pragma unroll
    for (int s = 0; s < 8; s++) {
        int idx = s * 4 + w; // 0..31 -> (b, fo)
        int b = idx >> 4, fo = idx & 15;
        float4 o;
        o.x = Xs[b][lane][(fo * 4 + 0 + lane) & 63];
        o.y = Xs[b][lane][(fo * 4 + 1 + lane) & 63];
        o.z = Xs[b][lane][(fo * 4 + 2 + lane) & 63];
        o.w = Xs[b][lane][(fo * 4 + 3 + lane) & 63];
        ((float4*)xq)[((size_t)(blk * 2 + b) * 16 + fo) * 64 + lane] = o;
    }

    // fa/phi: lanes = f, shuffle reduce; each wave owns 32 (b,i) pairs
    for (int s = 0; s < 32; s++) {
        int pair = w * 32 + s;
        int b = pair >> 6, i = pair & 63;
        float v = Xs[b][i][(lane + i) & 63] * W_A[i * 64 + lane];
#pragma unroll
        for (int k = 1; k < 64; k <<= 1) v += __shfl_xor(v, k);
        if (lane == 0) {
            float ae = v * 0.125f + B_A[i];
            float fv = 1.0f / (1.0f + expf(-ae));
            size_t o = (size_t)(blk * 2 + b) * 64 + i;
            fa[o] = fv;
            phi[o] = fv * eb[i];
        }
    }
}

// ---------------------------------------------------------------------------
// kA: tF[b][i][h] = (x[b][i][:] @ W_F1[i]) * 0.125
// grid (64 b-tiles, 64 i). Line-per-instr staging loads (bl=t>>2, q=t&3).
// ---------------------------------------------------------------------------
__global__ __launch_bounds__(256, 4)
void kA(const float* __restrict__ x, const float* __restrict__ W_F1,
        float* __restrict__ tF)
{
    __shared__ float XT[64][68]; // XT[f][b]
    __shared__ float Ws[64][68]; // Ws[f][h]
    const int i = blockIdx.y;
    const int b0 = blockIdx.x * 64;
    const int t = threadIdx.x;
    const int bl = t >> 2, q = t & 3;

    {
        const float* src = x + ((size_t)(b0 + bl) * IC + i) * DIM + q * 4;
#pragma unroll
        for (int j4 = 0; j4 < 4; j4++) { // each instr: one 64B line per row
            float4 v = *(const float4*)(src + j4 * 16);
            int f = q * 4 + j4 * 16;
            XT[f + 0][bl] = v.x; XT[f + 1][bl] = v.y;
            XT[f + 2][bl] = v.z; XT[f + 3][bl] = v.w;
        }
        const float* wsrc = W_F1 + ((size_t)i * DIM + bl) * DIM + q * 4;
#pragma unroll
        for (int j4 = 0; j4 < 4; j4++)
            *(float4*)&Ws[bl][q * 4 + j4 * 16] = *(const float4*)(wsrc + j4 * 16);
    }
    __syncthreads();

    const int tr = t >> 4, tc = t & 15;
    float acc[4][4];
#pragma unroll
    for (int r = 0; r < 4; r++)
#pragma unroll
        for (int c = 0; c < 4; c++) acc[r][c] = 0.f;

#pragma unroll 8
    for (int k = 0; k < 64; k++) {
        float4 a = *(const float4*)&XT[k][tr * 4];
        float4 w = *(const float4*)&Ws[k][tc * 4];
        float ar[4] = {a.x, a.y, a.z, a.w};
#pragma unroll
        for (int r = 0; r < 4; r++) {
            acc[r][0] += ar[r] * w.x; acc[r][1] += ar[r] * w.y;
            acc[r][2] += ar[r] * w.z; acc[r][3] += ar[r] * w.w;
        }
    }
#pragma unroll
    for (int r = 0; r < 4; r++) {
        float4 o;
        o.x = acc[r][0] * 0.125f; o.y = acc[r][1] * 0.125f;
        o.z = acc[r][2] * 0.125f; o.w = acc[r][3] * 0.125f;
        *(float4*)&tF[((size_t)(b0 + tr * 4 + r) * IC + i) * DIM + tc * 4] = o;
    }
}

// ---------------------------------------------------------------------------
// kS: s[b][h] = sum_i phi[b][i] * tF[b][i][h].  grid 1024 (4 b / block).
// ---------------------------------------------------------------------------
__global__ __launch_bounds__(256, 4)
void kS(const float* __restrict__ phi, const float* __restrict__ tF,
        float* __restrict__ s)
{
    __shared__ float ph[4 * 64];
    const int b0 = blockIdx.x * 4;
    const int t = threadIdx.x;
    ph[t] = phi[(size_t)b0 * IC + t];
    __syncthreads();
    const int g = t >> 6, h = t & 63;
    const float* tfp = tF + ((size_t)(b0 + g) * IC) * DIM + h;
    float a = 0.f;
#pragma unroll 8
    for (int i = 0; i < IC; i++)
        a += ph[g * 64 + i] * tfp[(size_t)i * DIM];
    s[(size_t)(b0 + g) * DIM + h] = a;
}

// ---------------------------------------------------------------------------
// kXG: per (b-tile 64, m): three chained 64x64x64 GEMMs out of LDS.
// Staging loads reordered to line-per-instr (bl=t>>2, q=t&3).
// ---------------------------------------------------------------------------
__global__ __launch_bounds__(256, 4)
void kXG(const float* __restrict__ s, const float* __restrict__ WF2t,
         const float* __restrict__ B_F2, const float* __restrict__ W_G1,
         const float* __restrict__ W_G2, const float* __restrict__ B_G2,
         const float* __restrict__ gam, const float* __restrict__ bet,
         float* __restrict__ xhat, float* __restrict__ out, const int last)
{
    __shared__ float A[64][68];  // sT -> xnT -> tGT  (A[k][b])
    __shared__ float Wb[64][68]; // W panel [k][col]
    const int b0 = blockIdx.x * 64;
    const int m = blockIdx.y;
    const int t = threadIdx.x;
    const int bl = t >> 2, q = t & 3;
    const int tr = t >> 4, tc = t & 15;

    { // stage sT + W_F2t panel
        const float* src = s + (size_t)(b0 + bl) * DIM + q * 4;
#pragma unroll
        for (int j4 = 0; j4 < 4; j4++) {
            float4 v = *(const float4*)(src + j4 * 16);
            int f = q * 4 + j4 * 16;
            A[f + 0][bl] = v.x; A[f + 1][bl] = v.y;
            A[f + 2][bl] = v.z; A[f + 3][bl] = v.w;
        }
        const float* wsrc = WF2t + ((size_t)bl * OC + m) * DIM + q * 4;
#pragma unroll
        for (int j4 = 0; j4 < 4; j4++)
            *(float4*)&Wb[bl][q * 4 + j4 * 16] = *(const float4*)(wsrc + j4 * 16);
    }
    __syncthreads();

    float acc[4][4];
#pragma unroll
    for (int r = 0; r < 4; r++)
#pragma unroll
        for (int c = 0; c < 4; c++) acc[r][c] = 0.f;
#pragma unroll 8
    for (int k = 0; k < 64; k++) {
        float4 a = *(const float4*)&A[k][tr * 4];
        float4 w = *(const float4*)&Wb[k][tc * 4];
        float ar[4] = {a.x, a.y, a.z, a.w};
#pragma unroll
        for (int r = 0; r < 4; r++) {
            acc[r][0] += ar[r] * w.x; acc[r][1] += ar[r] * w.y;
            acc[r][2] += ar[r] * w.z; acc[r][3] += ar[r] * w.w;
        }
    }
    {
        float4 bf = *(const float4*)&B_F2[m * DIM + tc * 4];
#pragma unroll
        for (int r = 0; r < 4; r++) {
            acc[r][0] += bf.x; acc[r][1] += bf.y;
            acc[r][2] += bf.z; acc[r][3] += bf.w;
        }
    }
    if (last) {
#pragma unroll
        for (int r = 0; r < 4; r++)
            *(float4*)&out[((size_t)(b0 + tr * 4 + r) * OC + m) * DIM + tc * 4] =
                make_float4(acc[r][0], acc[r][1], acc[r][2], acc[r][3]);
        return;
    }
    { // LayerNorm rows (row = b, spread over 16 lanes sharing tr)
        float4 gv = *(const float4*)&gam[tc * 4];
        float4 bv = *(const float4*)&bet[tc * 4];
#pragma unroll
        for (int r = 0; r < 4; r++) {
            float sum = acc[r][0] + acc[r][1] + acc[r][2] + acc[r][3];
            float sq = acc[r][0] * acc[r][0] + acc[r][1] * acc[r][1] +
                       acc[r][2] * acc[r][2] + acc[r][3] * acc[r][3];
#pragma unroll
            for (int k = 1; k <= 8; k <<= 1) {
                sum += __shfl_xor(sum, k);
                sq  += __shfl_xor(sq, k);
            }
            float mu = sum * (1.0f / 64.0f);
            float var = sq * (1.0f / 64.0f) - mu * mu;
            float rs = 1.0f / sqrtf(var + 1e-5f);
            acc[r][0] = (acc[r][0] - mu) * rs * gv.x + bv.x;
            acc[r][1] = (acc[r][1] - mu) * rs * gv.y + bv.y;
            acc[r][2] = (acc[r][2] - mu) * rs * gv.z + bv.z;
            acc[r][3] = (acc[r][3] - mu) * rs * gv.w + bv.w;
        }
    }
    __syncthreads();
    { // A <- xnorm^T ; Wb <- W_G1
#pragma unroll
        for (int r = 0; r < 4; r++)
#pragma unroll
            for (int c = 0; c < 4; c++)
                A[tc * 4 + c][tr * 4 + r] = acc[r][c];
        const float* wsrc = W_G1 + (size_t)bl * DIM + q * 4;
#pragma unroll
        for (int j4 = 0; j4 < 4; j4++)
            *(float4*)&Wb[bl][q * 4 + j4 * 16] = *(const float4*)(wsrc + j4 * 16);
    }
    __syncthreads();

    float tg[4][4];
#pragma unroll
    for (int r = 0; r < 4; r++)
#pragma unroll
        for (int c = 0; c < 4; c++) tg[r][c] = 0.f;
#pragma unroll 8
    for (int k = 0; k < 64; k++) {
        float4 a = *(const float4*)&A[k][tr * 4];
        float4 w = *(const float4*)&Wb[k][tc * 4];
        float ar[4] = {a.x, a.y, a.z, a.w};
#pragma unroll
        for (int r = 0; r < 4; r++) {
            tg[r][0] += ar[r] * w.x; tg[r][1] += ar[r] * w.y;
            tg[r][2] += ar[r] * w.z; tg[r][3] += ar[r] * w.w;
        }
    }
    __syncthreads();
    { // A <- tG^T ; Wb <- W_G2[m]
#pragma unroll
        for (int r = 0; r < 4; r++)
#pragma unroll
            for (int c = 0; c < 4; c++)
                A[tc * 4 + c][tr * 4 + r] = tg[r][c];
        const float* wsrc = W_G2 + ((size_t)m * DIM + bl) * DIM + q * 4;
#pragma unroll
        for (int j4 = 0; j4 < 4; j4++)
            *(float4*)&Wb[bl][q * 4 + j4 * 16] = *(const float4*)(wsrc + j4 * 16);
    }
    __syncthreads();

    float xh[4][4];
    {
        float4 bg = *(const float4*)&B_G2[m * DIM + tc * 4];
#pragma unroll
        for (int r = 0; r < 4; r++) {
            xh[r][0] = bg.x; xh[r][1] = bg.y; xh[r][2] = bg.z; xh[r][3] = bg.w;
        }
    }
#pragma unroll 8
    for (int k = 0; k < 64; k++) {
        float4 a = *(const float4*)&A[k][tr * 4];
        float4 w = *(const float4*)&Wb[k][tc * 4];
        float ar[4] = {a.x, a.y, a.z, a.w};
#pragma unroll
        for (int r = 0; r < 4; r++) {
            xh[r][0] += ar[r] * w.x; xh[r][1] += ar[r] * w.y;
            xh[r][2] += ar[r] * w.z; xh[r][3] += ar[r] * w.w;
        }
    }
#pragma unroll
    for (int r = 0; r < 4; r++)
        *(float4*)&xhat[((size_t)(b0 + tr * 4 + r) * OC + m) * DIM + tc * 4] =
            make_float4(xh[r][0], xh[r][1], xh[r][2], xh[r][3]);
}

// ---------------------------------------------------------------------------
// kC: consistency + softmax + phi. grid 512 (8 b/block). x read via xq
// (fully coalesced: each instr = contiguous 1KB).
// ---------------------------------------------------------------------------
__global__ __launch_bounds__(256, 2)
void kC(const float* __restrict__ xq, const float* __restrict__ xhat,
        const float* __restrict__ WSt2, const float* __restrict__ BSt,
        const float* __restrict__ cb, const float* __restrict__ db,
        const float* __restrict__ fa, float* __restrict__ phi)
{
    __shared__ float buf[8704];
    const int b0 = blockIdx.x * 8;
    const int t = threadIdx.x;
    const int w = t >> 6, lane = t & 63;

    {
        const float4* src = (const float4*)(xhat + (size_t)b0 * OC * DIM);
        float4* dst = (float4*)buf;
#pragma unroll
        for (int j = 0; j < 8; j++) dst[t + j * 256] = src[t + j * 256];
    }
    __syncthreads();

    float acc[8][4];
#pragma unroll
    for (int k = 0; k < 4; k++) {
        float bs = BSt[(w * 4 + k) * IC + lane];
#pragma unroll
        for (int g = 0; g < 8; g++) acc[g][k] = bs;
    }

    const float4* xq4 = (const float4*)xq;
    for (int fc = 0; fc < 64; fc += 16) {
        float wreg[4][16];
#pragma unroll
        for (int k = 0; k < 4; k++) {
            int m = w * 4 + k;
#pragma unroll
            for (int q2 = 0; q2 < 4; q2++) {
                float4 v = *(const float4*)&WSt2[(((size_t)m * 16 + (fc >> 2) + q2) * IC + lane) * 4];
                wreg[k][q2 * 4 + 0] = v.x; wreg[k][q2 * 4 + 1] = v.y;
                wreg[k][q2 * 4 + 2] = v.z; wreg[k][q2 * 4 + 3] = v.w;
            }
        }
#pragma unroll
        for (int g = 0; g < 8; g++) {
            float xr[16];
#pragma unroll
            for (int q2 = 0; q2 < 4; q2++) { // coalesced 1KB/instr
                float4 v = xq4[((size_t)(b0 + g) * 16 + (fc >> 2) + q2) * 64 + lane];
                xr[q2 * 4 + 0] = v.x; xr[q2 * 4 + 1] = v.y;
                xr[q2 * 4 + 2] = v.z; xr[q2 * 4 + 3] = v.w;
            }
#pragma unroll
            for (int k = 0; k < 4; k++) {
                int m = w * 4 + k;
                const float* hp = &buf[(g * OC + m) * DIM + fc];
                float hr[16];
#pragma unroll
                for (int q2 = 0; q2 < 4; q2++) {
                    float4 v = *(const float4*)(hp + q2 * 4);
                    hr[q2 * 4 + 0] = v.x; hr[q2 * 4 + 1] = v.y;
                    hr[q2 * 4 + 2] = v.z; hr[q2 * 4 + 3] = v.w;
                }
#pragma unroll
                for (int ff = 0; ff < 16; ff++)
                    acc[g][k] += xr[ff] * hr[ff] * wreg[k][ff];
            }
        }
    }
    __syncthreads();
#pragma unroll
    for (int g = 0; g < 8; g++)
#pragma unroll
        for (int k = 0; k < 4; k++)
            buf[(g * IC + lane) * 17 + w * 4 + k] = acc[g][k];
    __syncthreads();

    for (int p = t; p < 512; p += 256) {
        int g = p >> 6, i = p & 63;
        const float* row = &buf[(g * IC + i) * 17];
        float v[16], mx = -1e30f;
#pragma unroll
        for (int m = 0; m < OC; m++) { v[m] = row[m]; mx = fmaxf(mx, v[m]); }
        float sum = 0.f;
#pragma unroll
        for (int m = 0; m < OC; m++) { v[m] = expf(v[m] - mx); sum += v[m]; }
        float inv = 1.0f / sum;
        float a2 = 0.f;
#pragma unroll
        for (int m = 0; m < OC; m++) a2 += v[m] * inv * cb[i * OC + m];
        size_t bi = (size_t)(b0 + g) * IC + i;
        phi[bi] = fa[bi] * (a2 - db[i]);
    }
}

// ---------------------------------------------------------------------------
extern "C" void kernel_launch(void* const* d_in, const int* in_sizes, int n_in,
                              void* d_out, int out_size, void* d_ws, size_t ws_size,
                              hipStream_t stream)
{
    const float* x    = (const float*)d_in[0];
    const float* W_A  = (const float*)d_in[1];
    const float* B_A  = (const float*)d_in[2];
    const float* W_F1 = (const float*)d_in[3];
    const float* W_F2 = (const float*)d_in[4];
    const float* B_F2 = (const float*)d_in[5];
    const float* W_G1 = (const float*)d_in[6];
    const float* W_G2 = (const float*)d_in[7];
    const float* B_G2 = (const float*)d_in[8];
    const float* gam  = (const float*)d_in[9];
    const float* bet  = (const float*)d_in[10];
    const float* W_S  = (const float*)d_in[11];
    const float* B_S  = (const float*)d_in[12];
    const float* bu   = (const float*)d_in[13];
    const float* bi_  = (const float*)d_in[14];

    float* ws   = (float*)d_ws;
    float* tF   = ws;                          // 16777216
    float* xq   = tF + 16777216;               // 16777216
    float* fa   = xq + 16777216;               // 262144
    float* phi  = fa + 262144;                 // 262144
    float* s    = phi + 262144;                // 262144
    float* xhat = s + 262144;                  // 4194304
    float* WF2t = xhat + 4194304;              // 65536
    float* WSt2 = WF2t + 65536;                // 65536
    float* BSt  = WSt2 + 65536;                // 1024
    float* cb   = BSt + 1024;                  // 1024
    float* db   = cb + 1024;                   // 64
    float* eb   = db + 64;                     // 64
    float* out  = (float*)d_out;

    kSetup<<<256, 256, 0, stream>>>(W_F2, W_S, B_S, bu, bi_, WF2t, WSt2, BSt, cb, db, eb);
    kT<<<2048, 256, 0, stream>>>(x, W_A, B_A, eb, xq, fa, phi);
    kA<<<dim3(64, 64), 256, 0, stream>>>(x, W_F1, tF);
    for (int it = 0; it < 3; ++it) {
        kS<<<1024, 256, 0, stream>>>(phi, tF, s);
        kXG<<<dim3(64, 16), 256, 0, stream>>>(s, WF2t, B_F2, W_G1, W_G2, B_G2,
                                              gam, bet, xhat, out, it == 2 ? 1 : 0);
        if (it < 2)
            kC<<<512, 256, 0, stream>>>(xq, xhat, WSt2, BSt, cb, db, fa, phi);
    }
}

// Round 5
// 364.263 us; speedup vs baseline: 1.2800x; 1.0760x over previous
//
#include <hip/hip_runtime.h>
#include <math.h>

#define IC 64
#define OC 16
#define DIM 64

// ---------------------------------------------------------------------------
// kSetup: weight transposes + beta folding.
//  WF2t[h][m][d] = W_F2[m][h][d]
//  WSt2[m][fo][i][fi] = W_S[i][m][fo*4+fi]   (lane-i coalesced float4)
//  BSt[m][i] = B_S[i][m]; cb[i][m]=bu+bi; db[i]=sum_m bi; eb[i]=sum_m cb/16 - db
// ---------------------------------------------------------------------------
__global__ void kSetup(const float* __restrict__ W_F2, const float* __restrict__ W_S,
                       const float* __restrict__ B_S, const float* __restrict__ bu,
                       const float* __restrict__ bi_,
                       float* __restrict__ WF2t, float* __restrict__ WSt2,
                       float* __restrict__ BSt, float* __restrict__ cb,
                       float* __restrict__ db, float* __restrict__ eb)
{
    int e = blockIdx.x * 256 + threadIdx.x; // 0..65535
    {
        int h = e >> 10, m = (e >> 6) & 15, d = e & 63;
        WF2t[e] = W_F2[((size_t)m * 64 + h) * 64 + d];
    }
    {
        int m = e >> 12, fo = (e >> 8) & 15, i = (e >> 2) & 63, fi = e & 3;
        WSt2[e] = W_S[((size_t)i * 16 + m) * 64 + fo * 4 + fi];
    }
    if (e < 1024) {
        int m = e >> 6, i = e & 63;
        BSt[e] = B_S[i * 16 + m];
        cb[e] = bu[e] + bi_[e];
    }
    if (e < 64) {
        float sc = 0.f, sd = 0.f;
        for (int m = 0; m < 16; m++) {
            sc += bu[e * 16 + m] + bi_[e * 16 + m];
            sd += bi_[e * 16 + m];
        }
        db[e] = sd;
        eb[e] = sc * (1.0f / 16.0f) - sd;
    }
}

// ---------------------------------------------------------------------------
// kT: coalesced x pass -> xq[b][fo][i][fi]; fa/phi0.
// 2 batch/block, 2048 blocks. LDS pitch 65 (65 mod 32 = 1 -> every access
// pattern is exactly 2-way bank-aliased = free).
// fa: 2 threads per (b,i) pair, 32 unrolled LDS reads + 1 shuffle.
// ---------------------------------------------------------------------------
__global__ __launch_bounds__(256, 4)
void kT(const float* __restrict__ x, const float* __restrict__ W_A,
        const float* __restrict__ B_A, const float* __restrict__ eb,
        float* __restrict__ xq, float* __restrict__ fa, float* __restrict__ phi)
{
    __shared__ float Xs[2 * 64 * 65];
    const int t = threadIdx.x;
    const int blk = blockIdx.x;

    const float4* x4 = (const float4*)x;
#pragma unroll
    for (int s = 0; s < 8; s++) { // stage 2 batch rows, 1KB/instr coalesced
        int p = s * 256 + t;
        float4 v = x4[(size_t)blk * 2048 + p];
        int b = p >> 10, i = (p >> 4) & 63, fo = p & 15;
        float* row = &Xs[(b * 64 + i) * 65 + fo * 4];
        row[0] = v.x; row[1] = v.y; row[2] = v.z; row[3] = v.w;
    }
    __syncthreads();

    const int lane = t & 63, w = t >> 6;
#pragma unroll
    for (int s = 0; s < 8; s++) { // xq: lane=i, coalesced 1KB writes
        int idx = s * 4 + w;
        int b = idx >> 4, fo = idx & 15;
        const float* row = &Xs[(b * 64 + lane) * 65 + fo * 4];
        ((float4*)xq)[((size_t)(blk * 2 + b) * 16 + fo) * 64 + lane] =
            make_float4(row[0], row[1], row[2], row[3]);
    }

    { // fa/phi: pair p=(b,i), half h sums 32 f's
        int p = t >> 1, h = t & 1;
        int b = p >> 6, i = p & 63;
        const float* row = &Xs[(b * 64 + i) * 65 + h * 32];
        const float* wa = W_A + i * 64 + h * 32;
        float v = 0.f;
#pragma unroll
        for (int j = 0; j < 32; j++) v += row[j] * wa[j];
        v += __shfl_xor(v, 1);
        if (h == 0) {
            float ae = v * 0.125f + B_A[i];
            float fv = 1.0f / (1.0f + expf(-ae));
            size_t o = (size_t)(blk * 2 + b) * 64 + i;
            fa[o] = fv;
            phi[o] = fv * eb[i];
        }
    }
}

// ---------------------------------------------------------------------------
// kA: tF[b][i][h] = (x[b][i][:] @ W_F1[i]) * 0.125  (f32)
// grid (64 b-tiles, 64 i). Line-per-instr staging loads.
// ---------------------------------------------------------------------------
__global__ __launch_bounds__(256, 4)
void kA(const float* __restrict__ x, const float* __restrict__ W_F1,
        float* __restrict__ tF)
{
    __shared__ float XT[64][68]; // XT[f][b]
    __shared__ float Ws[64][68]; // Ws[f][h]
    const int i = blockIdx.y;
    const int b0 = blockIdx.x * 64;
    const int t = threadIdx.x;
    const int bl = t >> 2, q = t & 3;

    {
        const float* src = x + ((size_t)(b0 + bl) * IC + i) * DIM + q * 4;
#pragma unroll
        for (int j4 = 0; j4 < 4; j4++) { // each instr: one 64B line per row
            float4 v = *(const float4*)(src + j4 * 16);
            int f = q * 4 + j4 * 16;
            XT[f + 0][bl] = v.x; XT[f + 1][bl] = v.y;
            XT[f + 2][bl] = v.z; XT[f + 3][bl] = v.w;
        }
        const float* wsrc = W_F1 + ((size_t)i * DIM + bl) * DIM + q * 4;
#pragma unroll
        for (int j4 = 0; j4 < 4; j4++)
            *(float4*)&Ws[bl][q * 4 + j4 * 16] = *(const float4*)(wsrc + j4 * 16);
    }
    __syncthreads();

    const int tr = t >> 4, tc = t & 15;
    float acc[4][4];
#pragma unroll
    for (int r = 0; r < 4; r++)
#pragma unroll
        for (int c = 0; c < 4; c++) acc[r][c] = 0.f;

#pragma unroll 8
    for (int k = 0; k < 64; k++) {
        float4 a = *(const float4*)&XT[k][tr * 4];
        float4 w = *(const float4*)&Ws[k][tc * 4];
        float ar[4] = {a.x, a.y, a.z, a.w};
#pragma unroll
        for (int r = 0; r < 4; r++) {
            acc[r][0] += ar[r] * w.x; acc[r][1] += ar[r] * w.y;
            acc[r][2] += ar[r] * w.z; acc[r][3] += ar[r] * w.w;
        }
    }
#pragma unroll
    for (int r = 0; r < 4; r++) {
        float4 o;
        o.x = acc[r][0] * 0.125f; o.y = acc[r][1] * 0.125f;
        o.z = acc[r][2] * 0.125f; o.w = acc[r][3] * 0.125f;
        *(float4*)&tF[((size_t)(b0 + tr * 4 + r) * IC + i) * DIM + tc * 4] = o;
    }
}

// ---------------------------------------------------------------------------
// kS: s[b][h] = sum_i phi[b][i] * tF[b][i][h].  1024 blocks, wave per b.
// lane = (ig = i-group, hq = h-quad); float4 tF loads; cross-ig shuffle reduce.
// ---------------------------------------------------------------------------
__global__ __launch_bounds__(256, 4)
void kS(const float* __restrict__ phi, const float* __restrict__ tF,
        float* __restrict__ s)
{
    __shared__ float ph[4 * 64];
    const int t = threadIdx.x;
    const int b0 = blockIdx.x * 4;
    ph[t] = phi[(size_t)b0 * 64 + t];
    __syncthreads();

    const int w = t >> 6, lane = t & 63;
    const int ig = lane >> 4, hq = lane & 15;
    const int b = b0 + w;
    const float4* tf4 = (const float4*)(tF + ((size_t)b * 64 + ig * 16) * 64) + hq;
    float4 a = make_float4(0.f, 0.f, 0.f, 0.f);
#pragma unroll
    for (int k = 0; k < 16; k++) {
        float p = ph[w * 64 + ig * 16 + k];
        float4 v = tf4[k * 16];
        a.x += p * v.x; a.y += p * v.y; a.z += p * v.z; a.w += p * v.w;
    }
#pragma unroll
    for (int k = 16; k <= 32; k <<= 1) {
        a.x += __shfl_xor(a.x, k); a.y += __shfl_xor(a.y, k);
        a.z += __shfl_xor(a.z, k); a.w += __shfl_xor(a.w, k);
    }
    if (ig == 0)
        ((float4*)(s + (size_t)b * 64))[hq] = a;
}

// ---------------------------------------------------------------------------
// kXG: per (b-tile 64, m): three chained 64x64x64 GEMMs out of LDS.
// ---------------------------------------------------------------------------
__global__ __launch_bounds__(256, 4)
void kXG(const float* __restrict__ s, const float* __restrict__ WF2t,
         const float* __restrict__ B_F2, const float* __restrict__ W_G1,
         const float* __restrict__ W_G2, const float* __restrict__ B_G2,
         const float* __restrict__ gam, const float* __restrict__ bet,
         float* __restrict__ xhat, float* __restrict__ out, const int last)
{
    __shared__ float A[64][68];  // sT -> xnT -> tGT  (A[k][b])
    __shared__ float Wb[64][68]; // W panel [k][col]
    const int b0 = blockIdx.x * 64;
    const int m = blockIdx.y;
    const int t = threadIdx.x;
    const int bl = t >> 2, q = t & 3;
    const int tr = t >> 4, tc = t & 15;

    { // stage sT + W_F2t panel
        const float* src = s + (size_t)(b0 + bl) * DIM + q * 4;
#pragma unroll
        for (int j4 = 0; j4 < 4; j4++) {
            float4 v = *(const float4*)(src + j4 * 16);
            int f = q * 4 + j4 * 16;
            A[f + 0][bl] = v.x; A[f + 1][bl] = v.y;
            A[f + 2][bl] = v.z; A[f + 3][bl] = v.w;
        }
        const float* wsrc = WF2t + ((size_t)bl * OC + m) * DIM + q * 4;
#pragma unroll
        for (int j4 = 0; j4 < 4; j4++)
            *(float4*)&Wb[bl][q * 4 + j4 * 16] = *(const float4*)(wsrc + j4 * 16);
    }
    __syncthreads();

    float acc[4][4];
#pragma unroll
    for (int r = 0; r < 4; r++)
#pragma unroll
        for (int c = 0; c < 4; c++) acc[r][c] = 0.f;
#pragma unroll 8
    for (int k = 0; k < 64; k++) {
        float4 a = *(const float4*)&A[k][tr * 4];
        float4 w = *(const float4*)&Wb[k][tc * 4];
        float ar[4] = {a.x, a.y, a.z, a.w};
#pragma unroll
        for (int r = 0; r < 4; r++) {
            acc[r][0] += ar[r] * w.x; acc[r][1] += ar[r] * w.y;
            acc[r][2] += ar[r] * w.z; acc[r][3] += ar[r] * w.w;
        }
    }
    {
        float4 bf = *(const float4*)&B_F2[m * DIM + tc * 4];
#pragma unroll
        for (int r = 0; r < 4; r++) {
            acc[r][0] += bf.x; acc[r][1] += bf.y;
            acc[r][2] += bf.z; acc[r][3] += bf.w;
        }
    }
    if (last) {
#pragma unroll
        for (int r = 0; r < 4; r++)
            *(float4*)&out[((size_t)(b0 + tr * 4 + r) * OC + m) * DIM + tc * 4] =
                make_float4(acc[r][0], acc[r][1], acc[r][2], acc[r][3]);
        return;
    }
    { // LayerNorm rows (row = b, spread over 16 lanes sharing tr)
        float4 gv = *(const float4*)&gam[tc * 4];
        float4 bv = *(const float4*)&bet[tc * 4];
#pragma unroll
        for (int r = 0; r < 4; r++) {
            float sum = acc[r][0] + acc[r][1] + acc[r][2] + acc[r][3];
            float sq = acc[r][0] * acc[r][0] + acc[r][1] * acc[r][1] +
                       acc[r][2] * acc[r][2] + acc[r][3] * acc[r][3];
#pragma unroll
            for (int k = 1; k <= 8; k <<= 1) {
                sum += __shfl_xor(sum, k);
                sq  += __shfl_xor(sq, k);
            }
            float mu = sum * (1.0f / 64.0f);
            float var = sq * (1.0f / 64.0f) - mu * mu;
            float rs = 1.0f / sqrtf(var + 1e-5f);
            acc[r][0] = (acc[r][0] - mu) * rs * gv.x + bv.x;
            acc[r][1] = (acc[r][1] - mu) * rs * gv.y + bv.y;
            acc[r][2] = (acc[r][2] - mu) * rs * gv.z + bv.z;
            acc[r][3] = (acc[r][3] - mu) * rs * gv.w + bv.w;
        }
    }
    __syncthreads();
    { // A <- xnorm^T ; Wb <- W_G1
#pragma unroll
        for (int r = 0; r < 4; r++)
#pragma unroll
            for (int c = 0; c < 4; c++)
                A[tc * 4 + c][tr * 4 + r] = acc[r][c];
        const float* wsrc = W_G1 + (size_t)bl * DIM + q * 4;
#pragma unroll
        for (int j4 = 0; j4 < 4; j4++)
            *(float4*)&Wb[bl][q * 4 + j4 * 16] = *(const float4*)(wsrc + j4 * 16);
    }
    __syncthreads();

    float tg[4][4];
#pragma unroll
    for (int r = 0; r < 4; r++)
#pragma unroll
        for (int c = 0; c < 4; c++) tg[r][c] = 0.f;
#pragma unroll 8
    for (int k = 0; k < 64; k++) {
        float4 a = *(const float4*)&A[k][tr * 4];
        float4 w = *(const float4*)&Wb[k][tc * 4];
        float ar[4] = {a.x, a.y, a.z, a.w};
#pragma unroll
        for (int r = 0; r < 4; r++) {
            tg[r][0] += ar[r] * w.x; tg[r][1] += ar[r] * w.y;
            tg[r][2] += ar[r] * w.z; tg[r][3] += ar[r] * w.w;
        }
    }
    __syncthreads();
    { // A <- tG^T ; Wb <- W_G2[m]
#pragma unroll
        for (int r = 0; r < 4; r++)
#pragma unroll
            for (int c = 0; c < 4; c++)
                A[tc * 4 + c][tr * 4 + r] = tg[r][c];
        const float* wsrc = W_G2 + ((size_t)m * DIM + bl) * DIM + q * 4;
#pragma unroll
        for (int j4 = 0; j4 < 4; j4++)
            *(float4*)&Wb[bl][q * 4 + j4 * 16] = *(const float4*)(wsrc + j4 * 16);
    }
    __syncthreads();

    float xh[4][4];
    {
        float4 bg = *(const float4*)&B_G2[m * DIM + tc * 4];
#pragma unroll
        for (int r = 0; r < 4; r++) {
            xh[r][0] = bg.x; xh[r][1] = bg.y; xh[r][2] = bg.z; xh[r][3] = bg.w;
        }
    }
#pragma unroll 8
    for (int k = 0; k < 64; k++) {
        float4 a = *(const float4*)&A[k][tr * 4];
        float4 w = *(const float4*)&Wb[k][tc * 4];
        float ar[4] = {a.x, a.y, a.z, a.w};
#pragma unroll
        for (int r = 0; r < 4; r++) {
            xh[r][0] += ar[r] * w.x; xh[r][1] += ar[r] * w.y;
            xh[r][2] += ar[r] * w.z; xh[r][3] += ar[r] * w.w;
        }
    }
#pragma unroll
    for (int r = 0; r < 4; r++)
        *(float4*)&xhat[((size_t)(b0 + tr * 4 + r) * OC + m) * DIM + tc * 4] =
            make_float4(xh[r][0], xh[r][1], xh[r][2], xh[r][3]);
}

// ---------------------------------------------------------------------------
// kC: consistency + softmax + phi. grid 512 (8 b/block). x via xq (coalesced).
// ---------------------------------------------------------------------------
__global__ __launch_bounds__(256, 2)
void kC(const float* __restrict__ xq, const float* __restrict__ xhat,
        const float* __restrict__ WSt2, const float* __restrict__ BSt,
        const float* __restrict__ cb, const float* __restrict__ db,
        const float* __restrict__ fa, float* __restrict__ phi)
{
    __shared__ float buf[8704];
    const int b0 = blockIdx.x * 8;
    const int t = threadIdx.x;
    const int w = t >> 6, lane = t & 63;

    {
        const float4* src = (const float4*)(xhat + (size_t)b0 * OC * DIM);
        float4* dst = (float4*)buf;
#pragma unroll
        for (int j = 0; j < 8; j++) dst[t + j * 256] = src[t + j * 256];
    }
    __syncthreads();

    float acc[8][4];
#pragma unroll
    for (int k = 0; k < 4; k++) {
        float bs = BSt[(w * 4 + k) * IC + lane];
#pragma unroll
        for (int g = 0; g < 8; g++) acc[g][k] = bs;
    }

    const float4* xq4 = (const float4*)xq;
    for (int fc = 0; fc < 64; fc += 16) {
        float wreg[4][16];
#pragma unroll
        for (int k = 0; k < 4; k++) {
            int m = w * 4 + k;
#pragma unroll
            for (int q2 = 0; q2 < 4; q2++) {
                float4 v = *(const float4*)&WSt2[(((size_t)m * 16 + (fc >> 2) + q2) * IC + lane) * 4];
                wreg[k][q2 * 4 + 0] = v.x; wreg[k][q2 * 4 + 1] = v.y;
                wreg[k][q2 * 4 + 2] = v.z; wreg[k][q2 * 4 + 3] = v.w;
            }
        }
#pragma unroll
        for (int g = 0; g < 8; g++) {
            float xr[16];
#pragma unroll
            for (int q2 = 0; q2 < 4; q2++) {
                float4 v = xq4[((size_t)(b0 + g) * 16 + (fc >> 2) + q2) * 64 + lane];
                xr[q2 * 4 + 0] = v.x; xr[q2 * 4 + 1] = v.y;
                xr[q2 * 4 + 2] = v.z; xr[q2 * 4 + 3] = v.w;
            }
#pragma unroll
            for (int k = 0; k < 4; k++) {
                int m = w * 4 + k;
                const float* hp = &buf[(g * OC + m) * DIM + fc];
                float hr[16];
#pragma unroll
                for (int q2 = 0; q2 < 4; q2++) {
                    float4 v = *(const float4*)(hp + q2 * 4);
                    hr[q2 * 4 + 0] = v.x; hr[q2 * 4 + 1] = v.y;
                    hr[q2 * 4 + 2] = v.z; hr[q2 * 4 + 3] = v.w;
                }
#pragma unroll
                for (int ff = 0; ff < 16; ff++)
                    acc[g][k] += xr[ff] * hr[ff] * wreg[k][ff];
            }
        }
    }
    __syncthreads();
#pragma unroll
    for (int g = 0; g < 8; g++)
#pragma unroll
        for (int k = 0; k < 4; k++)
            buf[(g * IC + lane) * 17 + w * 4 + k] = acc[g][k];
    __syncthreads();

    for (int p = t; p < 512; p += 256) {
        int g = p >> 6, i = p & 63;
        const float* row = &buf[(g * IC + i) * 17];
        float v[16], mx = -1e30f;
#pragma unroll
        for (int m = 0; m < OC; m++) { v[m] = row[m]; mx = fmaxf(mx, v[m]); }
        float sum = 0.f;
#pragma unroll
        for (int m = 0; m < OC; m++) { v[m] = expf(v[m] - mx); sum += v[m]; }
        float inv = 1.0f / sum;
        float a2 = 0.f;
#pragma unroll
        for (int m = 0; m < OC; m++) a2 += v[m] * inv * cb[i * OC + m];
        size_t bi = (size_t)(b0 + g) * IC + i;
        phi[bi] = fa[bi] * (a2 - db[i]);
    }
}

// ---------------------------------------------------------------------------
extern "C" void kernel_launch(void* const* d_in, const int* in_sizes, int n_in,
                              void* d_out, int out_size, void* d_ws, size_t ws_size,
                              hipStream_t stream)
{
    const float* x    = (const float*)d_in[0];
    const float* W_A  = (const float*)d_in[1];
    const float* B_A  = (const float*)d_in[2];
    const float* W_F1 = (const float*)d_in[3];
    const float* W_F2 = (const float*)d_in[4];
    const float* B_F2 = (const float*)d_in[5];
    const float* W_G1 = (const float*)d_in[6];
    const float* W_G2 = (const float*)d_in[7];
    const float* B_G2 = (const float*)d_in[8];
    const float* gam  = (const float*)d_in[9];
    const float* bet  = (const float*)d_in[10];
    const float* W_S  = (const float*)d_in[11];
    const float* B_S  = (const float*)d_in[12];
    const float* bu   = (const float*)d_in[13];
    const float* bi_  = (const float*)d_in[14];

    float* ws   = (float*)d_ws;
    float* tF   = ws;                          // 16777216
    float* xq   = tF + 16777216;               // 16777216
    float* fa   = xq + 16777216;               // 262144
    float* phi  = fa + 262144;                 // 262144
    float* s    = phi + 262144;                // 262144
    float* xhat = s + 262144;                  // 4194304
    float* WF2t = xhat + 4194304;              // 65536
    float* WSt2 = WF2t + 65536;                // 65536
    float* BSt  = WSt2 + 65536;                // 1024
    float* cb   = BSt + 1024;                  // 1024
    float* db   = cb + 1024;                   // 64
    float* eb   = db + 64;                     // 64
    float* out  = (float*)d_out;

    kSetup<<<256, 256, 0, stream>>>(W_F2, W_S, B_S, bu, bi_, WF2t, WSt2, BSt, cb, db, eb);
    kT<<<2048, 256, 0, stream>>>(x, W_A, B_A, eb, xq, fa, phi);
    kA<<<dim3(64, 64), 256, 0, stream>>>(x, W_F1, tF);
    for (int it = 0; it < 3; ++it) {
        kS<<<1024, 256, 0, stream>>>(phi, tF, s);
        kXG<<<dim3(64, 16), 256, 0, stream>>>(s, WF2t, B_F2, W_G1, W_G2, B_G2,
                                              gam, bet, xhat, out, it == 2 ? 1 : 0);
        if (it < 2)
            kC<<<512, 256, 0, stream>>>(xq, xhat, WSt2, BSt, cb, db, fa, phi);
    }
}

// Round 6
// 332.787 us; speedup vs baseline: 1.4011x; 1.0946x over previous
//
#include <hip/hip_runtime.h>
#include <math.h>

#define IC 64
#define OC 16
#define DIM 64

// ---------------------------------------------------------------------------
// kSetup: weight transposes + beta folding + WG12 fold.
//  WF2t[h][m][d] = W_F2[m][h][d]
//  WSt2[m][fo][i][fi] = W_S[i][m][fo*4+fi]   (lane-i coalesced float4)
//  WG12[m][d][f] = sum_h W_G1[d][h]*W_G2[m][h][f]   (folds GEMM2+GEMM3)
//  BSt[m][i] = B_S[i][m]; cb[i][m]=bu+bi; db[i]=sum_m bi; eb[i]=sum_m cb/16 - db
// ---------------------------------------------------------------------------
__global__ void kSetup(const float* __restrict__ W_F2, const float* __restrict__ W_S,
                       const float* __restrict__ B_S, const float* __restrict__ bu,
                       const float* __restrict__ bi_, const float* __restrict__ W_G1,
                       const float* __restrict__ W_G2,
                       float* __restrict__ WF2t, float* __restrict__ WSt2,
                       float* __restrict__ WG12,
                       float* __restrict__ BSt, float* __restrict__ cb,
                       float* __restrict__ db, float* __restrict__ eb)
{
    int e = blockIdx.x * 256 + threadIdx.x; // 0..65535
    {
        int h = e >> 10, m = (e >> 6) & 15, d = e & 63;
        WF2t[e] = W_F2[((size_t)m * 64 + h) * 64 + d];
    }
    {
        int m = e >> 12, fo = (e >> 8) & 15, i = (e >> 2) & 63, fi = e & 3;
        WSt2[e] = W_S[((size_t)i * 16 + m) * 64 + fo * 4 + fi];
    }
    { // WG12[m][d][f]
        int m = e >> 12, d = (e >> 6) & 63, f = e & 63;
        const float* g1 = W_G1 + d * 64;
        const float* g2 = W_G2 + (size_t)m * 4096 + f;
        float a = 0.f;
#pragma unroll 8
        for (int h = 0; h < 64; h++) a += g1[h] * g2[h * 64];
        WG12[e] = a;
    }
    if (e < 1024) {
        int m = e >> 6, i = e & 63;
        BSt[e] = B_S[i * 16 + m];
        cb[e] = bu[e] + bi_[e];
    }
    if (e < 64) {
        float sc = 0.f, sd = 0.f;
        for (int m = 0; m < 16; m++) {
            sc += bu[e * 16 + m] + bi_[e * 16 + m];
            sd += bi_[e * 16 + m];
        }
        db[e] = sd;
        eb[e] = sc * (1.0f / 16.0f) - sd;
    }
}

// ---------------------------------------------------------------------------
// kT: coalesced x pass -> xq[b][fo][i][fi]; fa/phi0. Pitch-65 LDS (2-way max).
// ---------------------------------------------------------------------------
__global__ __launch_bounds__(256, 4)
void kT(const float* __restrict__ x, const float* __restrict__ W_A,
        const float* __restrict__ B_A, const float* __restrict__ eb,
        float* __restrict__ xq, float* __restrict__ fa, float* __restrict__ phi)
{
    __shared__ float Xs[2 * 64 * 65];
    const int t = threadIdx.x;
    const int blk = blockIdx.x;

    const float4* x4 = (const float4*)x;
#pragma unroll
    for (int s = 0; s < 8; s++) { // stage 2 batch rows, 1KB/instr coalesced
        int p = s * 256 + t;
        float4 v = x4[(size_t)blk * 2048 + p];
        int b = p >> 10, i = (p >> 4) & 63, fo = p & 15;
        float* row = &Xs[(b * 64 + i) * 65 + fo * 4];
        row[0] = v.x; row[1] = v.y; row[2] = v.z; row[3] = v.w;
    }
    __syncthreads();

    const int lane = t & 63, w = t >> 6;
#pragma unroll
    for (int s = 0; s < 8; s++) { // xq: lane=i, coalesced 1KB writes
        int idx = s * 4 + w;
        int b = idx >> 4, fo = idx & 15;
        const float* row = &Xs[(b * 64 + lane) * 65 + fo * 4];
        ((float4*)xq)[((size_t)(blk * 2 + b) * 16 + fo) * 64 + lane] =
            make_float4(row[0], row[1], row[2], row[3]);
    }

    { // fa/phi: pair p=(b,i), half h sums 32 f's
        int p = t >> 1, h = t & 1;
        int b = p >> 6, i = p & 63;
        const float* row = &Xs[(b * 64 + i) * 65 + h * 32];
        const float* wa = W_A + i * 64 + h * 32;
        float v = 0.f;
#pragma unroll
        for (int j = 0; j < 32; j++) v += row[j] * wa[j];
        v += __shfl_xor(v, 1);
        if (h == 0) {
            float ae = v * 0.125f + B_A[i];
            float fv = 1.0f / (1.0f + expf(-ae));
            size_t o = (size_t)(blk * 2 + b) * 64 + i;
            fa[o] = fv;
            phi[o] = fv * eb[i];
        }
    }
}

// ---------------------------------------------------------------------------
// kA: tF[b][i][h] = (x[b][i][:] @ W_F1[i]) * 0.125  (f32)
// ---------------------------------------------------------------------------
__global__ __launch_bounds__(256, 4)
void kA(const float* __restrict__ x, const float* __restrict__ W_F1,
        float* __restrict__ tF)
{
    __shared__ float XT[64][68]; // XT[f][b]
    __shared__ float Ws[64][68]; // Ws[f][h]
    const int i = blockIdx.y;
    const int b0 = blockIdx.x * 64;
    const int t = threadIdx.x;
    const int bl = t >> 2, q = t & 3;

    {
        const float* src = x + ((size_t)(b0 + bl) * IC + i) * DIM + q * 4;
#pragma unroll
        for (int j4 = 0; j4 < 4; j4++) { // each instr: one 64B line per row
            float4 v = *(const float4*)(src + j4 * 16);
            int f = q * 4 + j4 * 16;
            XT[f + 0][bl] = v.x; XT[f + 1][bl] = v.y;
            XT[f + 2][bl] = v.z; XT[f + 3][bl] = v.w;
        }
        const float* wsrc = W_F1 + ((size_t)i * DIM + bl) * DIM + q * 4;
#pragma unroll
        for (int j4 = 0; j4 < 4; j4++)
            *(float4*)&Ws[bl][q * 4 + j4 * 16] = *(const float4*)(wsrc + j4 * 16);
    }
    __syncthreads();

    const int tr = t >> 4, tc = t & 15;
    float acc[4][4];
#pragma unroll
    for (int r = 0; r < 4; r++)
#pragma unroll
        for (int c = 0; c < 4; c++) acc[r][c] = 0.f;

#pragma unroll 8
    for (int k = 0; k < 64; k++) {
        float4 a = *(const float4*)&XT[k][tr * 4];
        float4 w = *(const float4*)&Ws[k][tc * 4];
        float ar[4] = {a.x, a.y, a.z, a.w};
#pragma unroll
        for (int r = 0; r < 4; r++) {
            acc[r][0] += ar[r] * w.x; acc[r][1] += ar[r] * w.y;
            acc[r][2] += ar[r] * w.z; acc[r][3] += ar[r] * w.w;
        }
    }
#pragma unroll
    for (int r = 0; r < 4; r++) {
        float4 o;
        o.x = acc[r][0] * 0.125f; o.y = acc[r][1] * 0.125f;
        o.z = acc[r][2] * 0.125f; o.w = acc[r][3] * 0.125f;
        *(float4*)&tF[((size_t)(b0 + tr * 4 + r) * IC + i) * DIM + tc * 4] = o;
    }
}

// ---------------------------------------------------------------------------
// kS: s[b][h] = sum_i phi[b][i] * tF[b][i][h].  1024 blocks, wave per b.
// ---------------------------------------------------------------------------
__global__ __launch_bounds__(256, 4)
void kS(const float* __restrict__ phi, const float* __restrict__ tF,
        float* __restrict__ s)
{
    __shared__ float ph[4 * 64];
    const int t = threadIdx.x;
    const int b0 = blockIdx.x * 4;
    ph[t] = phi[(size_t)b0 * 64 + t];
    __syncthreads();

    const int w = t >> 6, lane = t & 63;
    const int ig = lane >> 4, hq = lane & 15;
    const int b = b0 + w;
    const float4* tf4 = (const float4*)(tF + ((size_t)b * 64 + ig * 16) * 64) + hq;
    float4 a = make_float4(0.f, 0.f, 0.f, 0.f);
#pragma unroll
    for (int k = 0; k < 16; k++) {
        float p = ph[w * 64 + ig * 16 + k];
        float4 v = tf4[k * 16];
        a.x += p * v.x; a.y += p * v.y; a.z += p * v.z; a.w += p * v.w;
    }
#pragma unroll
    for (int k = 16; k <= 32; k <<= 1) {
        a.x += __shfl_xor(a.x, k); a.y += __shfl_xor(a.y, k);
        a.z += __shfl_xor(a.z, k); a.w += __shfl_xor(a.w, k);
    }
    if (ig == 0)
        ((float4*)(s + (size_t)b * 64))[hq] = a;
}

// ---------------------------------------------------------------------------
// kXG: per (b-tile 64, m): TWO chained 64x64x64 GEMMs out of LDS (WG12 fold).
//  GEMM1: x_out = s @ W_F2t[:,m,:] + B_F2[m]  -> (last: write out, exit)
//  LN in-register; xhat = xnorm @ WG12[m] + B_G2[m]
// ---------------------------------------------------------------------------
__global__ __launch_bounds__(256, 4)
void kXG(const float* __restrict__ s, const float* __restrict__ WF2t,
         const float* __restrict__ B_F2, const float* __restrict__ WG12,
         const float* __restrict__ B_G2,
         const float* __restrict__ gam, const float* __restrict__ bet,
         float* __restrict__ xhat, float* __restrict__ out, const int last)
{
    __shared__ float A[64][68];  // sT -> xnT  (A[k][b])
    __shared__ float Wb[64][68]; // W panel [k][col]
    const int b0 = blockIdx.x * 64;
    const int m = blockIdx.y;
    const int t = threadIdx.x;
    const int bl = t >> 2, q = t & 3;
    const int tr = t >> 4, tc = t & 15;

    { // stage sT + W_F2t panel
        const float* src = s + (size_t)(b0 + bl) * DIM + q * 4;
#pragma unroll
        for (int j4 = 0; j4 < 4; j4++) {
            float4 v = *(const float4*)(src + j4 * 16);
            int f = q * 4 + j4 * 16;
            A[f + 0][bl] = v.x; A[f + 1][bl] = v.y;
            A[f + 2][bl] = v.z; A[f + 3][bl] = v.w;
        }
        const float* wsrc = WF2t + ((size_t)bl * OC + m) * DIM + q * 4;
#pragma unroll
        for (int j4 = 0; j4 < 4; j4++)
            *(float4*)&Wb[bl][q * 4 + j4 * 16] = *(const float4*)(wsrc + j4 * 16);
    }
    __syncthreads();

    float acc[4][4];
#pragma unroll
    for (int r = 0; r < 4; r++)
#pragma unroll
        for (int c = 0; c < 4; c++) acc[r][c] = 0.f;
#pragma unroll 8
    for (int k = 0; k < 64; k++) {
        float4 a = *(const float4*)&A[k][tr * 4];
        float4 w = *(const float4*)&Wb[k][tc * 4];
        float ar[4] = {a.x, a.y, a.z, a.w};
#pragma unroll
        for (int r = 0; r < 4; r++) {
            acc[r][0] += ar[r] * w.x; acc[r][1] += ar[r] * w.y;
            acc[r][2] += ar[r] * w.z; acc[r][3] += ar[r] * w.w;
        }
    }
    {
        float4 bf = *(const float4*)&B_F2[m * DIM + tc * 4];
#pragma unroll
        for (int r = 0; r < 4; r++) {
            acc[r][0] += bf.x; acc[r][1] += bf.y;
            acc[r][2] += bf.z; acc[r][3] += bf.w;
        }
    }
    if (last) {
#pragma unroll
        for (int r = 0; r < 4; r++)
            *(float4*)&out[((size_t)(b0 + tr * 4 + r) * OC + m) * DIM + tc * 4] =
                make_float4(acc[r][0], acc[r][1], acc[r][2], acc[r][3]);
        return;
    }
    { // LayerNorm rows (row = b, spread over 16 lanes sharing tr)
        float4 gv = *(const float4*)&gam[tc * 4];
        float4 bv = *(const float4*)&bet[tc * 4];
#pragma unroll
        for (int r = 0; r < 4; r++) {
            float sum = acc[r][0] + acc[r][1] + acc[r][2] + acc[r][3];
            float sq = acc[r][0] * acc[r][0] + acc[r][1] * acc[r][1] +
                       acc[r][2] * acc[r][2] + acc[r][3] * acc[r][3];
#pragma unroll
            for (int k = 1; k <= 8; k <<= 1) {
                sum += __shfl_xor(sum, k);
                sq  += __shfl_xor(sq, k);
            }
            float mu = sum * (1.0f / 64.0f);
            float var = sq * (1.0f / 64.0f) - mu * mu;
            float rs = 1.0f / sqrtf(var + 1e-5f);
            acc[r][0] = (acc[r][0] - mu) * rs * gv.x + bv.x;
            acc[r][1] = (acc[r][1] - mu) * rs * gv.y + bv.y;
            acc[r][2] = (acc[r][2] - mu) * rs * gv.z + bv.z;
            acc[r][3] = (acc[r][3] - mu) * rs * gv.w + bv.w;
        }
    }
    __syncthreads(); // GEMM1 reads of A/Wb complete
    { // A <- xnorm^T ; Wb <- WG12[m]
#pragma unroll
        for (int r = 0; r < 4; r++)
#pragma unroll
            for (int c = 0; c < 4; c++)
                A[tc * 4 + c][tr * 4 + r] = acc[r][c];
        const float* wsrc = WG12 + ((size_t)m * DIM + bl) * DIM + q * 4;
#pragma unroll
        for (int j4 = 0; j4 < 4; j4++)
            *(float4*)&Wb[bl][q * 4 + j4 * 16] = *(const float4*)(wsrc + j4 * 16);
    }
    __syncthreads();

    float xh[4][4];
    {
        float4 bg = *(const float4*)&B_G2[m * DIM + tc * 4];
#pragma unroll
        for (int r = 0; r < 4; r++) {
            xh[r][0] = bg.x; xh[r][1] = bg.y; xh[r][2] = bg.z; xh[r][3] = bg.w;
        }
    }
#pragma unroll 8
    for (int k = 0; k < 64; k++) {
        float4 a = *(const float4*)&A[k][tr * 4];
        float4 w = *(const float4*)&Wb[k][tc * 4];
        float ar[4] = {a.x, a.y, a.z, a.w};
#pragma unroll
        for (int r = 0; r < 4; r++) {
            xh[r][0] += ar[r] * w.x; xh[r][1] += ar[r] * w.y;
            xh[r][2] += ar[r] * w.z; xh[r][3] += ar[r] * w.w;
        }
    }
#pragma unroll
    for (int r = 0; r < 4; r++)
        *(float4*)&xhat[((size_t)(b0 + tr * 4 + r) * OC + m) * DIM + tc * 4] =
            make_float4(xh[r][0], xh[r][1], xh[r][2], xh[r][3]);
}

// ---------------------------------------------------------------------------
// kC: consistency + softmax + phi. 4 b/block, grid 1024 (4 blocks/CU).
// fc-chunk 8 to keep VGPR <=128 at 4 waves/EU. xhat LDS reads are broadcasts.
// ---------------------------------------------------------------------------
__global__ __launch_bounds__(256, 4)
void kC(const float* __restrict__ xq, const float* __restrict__ xhat,
        const float* __restrict__ WSt2, const float* __restrict__ BSt,
        const float* __restrict__ cb, const float* __restrict__ db,
        const float* __restrict__ fa, float* __restrict__ phi)
{
    __shared__ float buf[4 * 64 * 17]; // xhat view: (g*16+m)*64+f (4096); cons view: (g*64+i)*17+m
    const int b0 = blockIdx.x * 4;
    const int t = threadIdx.x;
    const int w = t >> 6, lane = t & 63;

    { // stage xhat[b0..b0+4): 4096 floats, 1024 float4
        const float4* src = (const float4*)(xhat + (size_t)b0 * OC * DIM);
        float4* dst = (float4*)buf;
#pragma unroll
        for (int j = 0; j < 4; j++) dst[t + j * 256] = src[t + j * 256];
    }
    __syncthreads();

    float acc[4][4];
#pragma unroll
    for (int k = 0; k < 4; k++) {
        float bs = BSt[(w * 4 + k) * IC + lane];
#pragma unroll
        for (int g = 0; g < 4; g++) acc[g][k] = bs;
    }

    const float4* xq4 = (const float4*)xq;
    for (int fc = 0; fc < 64; fc += 8) {
        const int fo = fc >> 2;
        float wreg[4][8];
#pragma unroll
        for (int k = 0; k < 4; k++) {
            int m = w * 4 + k;
#pragma unroll
            for (int q2 = 0; q2 < 2; q2++) {
                float4 v = *(const float4*)&WSt2[(((size_t)m * 16 + fo + q2) * IC + lane) * 4];
                wreg[k][q2 * 4 + 0] = v.x; wreg[k][q2 * 4 + 1] = v.y;
                wreg[k][q2 * 4 + 2] = v.z; wreg[k][q2 * 4 + 3] = v.w;
            }
        }
#pragma unroll
        for (int g = 0; g < 4; g++) {
            float xr[8];
#pragma unroll
            for (int q2 = 0; q2 < 2; q2++) { // coalesced 1KB/instr
                float4 v = xq4[((size_t)(b0 + g) * 16 + fo + q2) * 64 + lane];
                xr[q2 * 4 + 0] = v.x; xr[q2 * 4 + 1] = v.y;
                xr[q2 * 4 + 2] = v.z; xr[q2 * 4 + 3] = v.w;
            }
#pragma unroll
            for (int k = 0; k < 4; k++) {
                int m = w * 4 + k;
                const float* hp = &buf[(g * OC + m) * DIM + fc];
                float hr[8];
#pragma unroll
                for (int q2 = 0; q2 < 2; q2++) { // same-addr broadcast reads
                    float4 v = *(const float4*)(hp + q2 * 4);
                    hr[q2 * 4 + 0] = v.x; hr[q2 * 4 + 1] = v.y;
                    hr[q2 * 4 + 2] = v.z; hr[q2 * 4 + 3] = v.w;
                }
#pragma unroll
                for (int ff = 0; ff < 8; ff++)
                    acc[g][k] += xr[ff] * hr[ff] * wreg[k][ff];
            }
        }
    }
    __syncthreads(); // all xhat reads done before overwrite
#pragma unroll
    for (int g = 0; g < 4; g++)
#pragma unroll
        for (int k = 0; k < 4; k++)
            buf[(g * IC + lane) * 17 + w * 4 + k] = acc[g][k];
    __syncthreads();

    { // softmax over m + phi: exactly 256 (g,i) pairs
        int g = t >> 6, i = t & 63;
        const float* row = &buf[(g * IC + i) * 17];
        float v[16], mx = -1e30f;
#pragma unroll
        for (int m = 0; m < OC; m++) { v[m] = row[m]; mx = fmaxf(mx, v[m]); }
        float sum = 0.f;
#pragma unroll
        for (int m = 0; m < OC; m++) { v[m] = expf(v[m] - mx); sum += v[m]; }
        float inv = 1.0f / sum;
        float a2 = 0.f;
#pragma unroll
        for (int m = 0; m < OC; m++) a2 += v[m] * inv * cb[i * OC + m];
        size_t bi = (size_t)(b0 + g) * IC + i;
        phi[bi] = fa[bi] * (a2 - db[i]);
    }
}

// ---------------------------------------------------------------------------
extern "C" void kernel_launch(void* const* d_in, const int* in_sizes, int n_in,
                              void* d_out, int out_size, void* d_ws, size_t ws_size,
                              hipStream_t stream)
{
    const float* x    = (const float*)d_in[0];
    const float* W_A  = (const float*)d_in[1];
    const float* B_A  = (const float*)d_in[2];
    const float* W_F1 = (const float*)d_in[3];
    const float* W_F2 = (const float*)d_in[4];
    const float* B_F2 = (const float*)d_in[5];
    const float* W_G1 = (const float*)d_in[6];
    const float* W_G2 = (const float*)d_in[7];
    const float* B_G2 = (const float*)d_in[8];
    const float* gam  = (const float*)d_in[9];
    const float* bet  = (const float*)d_in[10];
    const float* W_S  = (const float*)d_in[11];
    const float* B_S  = (const float*)d_in[12];
    const float* bu   = (const float*)d_in[13];
    const float* bi_  = (const float*)d_in[14];

    float* ws   = (float*)d_ws;
    float* tF   = ws;                          // 16777216
    float* xq   = tF + 16777216;               // 16777216
    float* fa   = xq + 16777216;               // 262144
    float* phi  = fa + 262144;                 // 262144
    float* s    = phi + 262144;                // 262144
    float* xhat = s + 262144;                  // 4194304
    float* WF2t = xhat + 4194304;              // 65536
    float* WSt2 = WF2t + 65536;                // 65536
    float* WG12 = WSt2 + 65536;                // 65536
    float* BSt  = WG12 + 65536;                // 1024
    float* cb   = BSt + 1024;                  // 1024
    float* db   = cb + 1024;                   // 64
    float* eb   = db + 64;                     // 64
    float* out  = (float*)d_out;

    kSetup<<<256, 256, 0, stream>>>(W_F2, W_S, B_S, bu, bi_, W_G1, W_G2,
                                    WF2t, WSt2, WG12, BSt, cb, db, eb);
    kT<<<2048, 256, 0, stream>>>(x, W_A, B_A, eb, xq, fa, phi);
    kA<<<dim3(64, 64), 256, 0, stream>>>(x, W_F1, tF);
    for (int it = 0; it < 3; ++it) {
        kS<<<1024, 256, 0, stream>>>(phi, tF, s);
        kXG<<<dim3(64, 16), 256, 0, stream>>>(s, WF2t, B_F2, WG12, B_G2,
                                              gam, bet, xhat, out, it == 2 ? 1 : 0);
        if (it < 2)
            kC<<<1024, 256, 0, stream>>>(xq, xhat, WSt2, BSt, cb, db, fa, phi);
    }
}

// Round 7
// 307.731 us; speedup vs baseline: 1.5152x; 1.0814x over previous
//
#include <hip/hip_runtime.h>
#include <math.h>

#define IC 64
#define OC 16
#define DIM 64

typedef __attribute__((ext_vector_type(8))) short bf16x8;
typedef __attribute__((ext_vector_type(4))) float f32x4;

__device__ __forceinline__ unsigned short f2bf(float f) { // RNE float->bf16
    unsigned int b = __float_as_uint(f);
    b += 0x7fffu + ((b >> 16) & 1u);
    return (unsigned short)(b >> 16);
}
__device__ __forceinline__ float bf2f(unsigned short h) {
    return __uint_as_float(((unsigned int)h) << 16);
}

// ---------------------------------------------------------------------------
// kSetup: weight transposes + beta folding + WG12 fold.
//  WF2t[h][m][d] = W_F2[m][h][d]
//  WSt2[m][fo][i][fi] = W_S[i][m][fo*4+fi]   (lane-i coalesced float4)
//  WG12[m][d][f] = sum_h W_G1[d][h]*W_G2[m][h][f]   (folds GEMM2+GEMM3)
//  BSt[m][i] = B_S[i][m]; cb[i][m]=bu+bi; db[i]=sum_m bi; eb[i]=sum_m cb/16 - db
// ---------------------------------------------------------------------------
__global__ void kSetup(const float* __restrict__ W_F2, const float* __restrict__ W_S,
                       const float* __restrict__ B_S, const float* __restrict__ bu,
                       const float* __restrict__ bi_, const float* __restrict__ W_G1,
                       const float* __restrict__ W_G2,
                       float* __restrict__ WF2t, float* __restrict__ WSt2,
                       float* __restrict__ WG12,
                       float* __restrict__ BSt, float* __restrict__ cb,
                       float* __restrict__ db, float* __restrict__ eb)
{
    int e = blockIdx.x * 256 + threadIdx.x; // 0..65535
    {
        int h = e >> 10, m = (e >> 6) & 15, d = e & 63;
        WF2t[e] = W_F2[((size_t)m * 64 + h) * 64 + d];
    }
    {
        int m = e >> 12, fo = (e >> 8) & 15, i = (e >> 2) & 63, fi = e & 3;
        WSt2[e] = W_S[((size_t)i * 16 + m) * 64 + fo * 4 + fi];
    }
    { // WG12[m][d][f]
        int m = e >> 12, d = (e >> 6) & 63, f = e & 63;
        const float* g1 = W_G1 + d * 64;
        const float* g2 = W_G2 + (size_t)m * 4096 + f;
        float a = 0.f;
#pragma unroll 8
        for (int h = 0; h < 64; h++) a += g1[h] * g2[h * 64];
        WG12[e] = a;
    }
    if (e < 1024) {
        int m = e >> 6, i = e & 63;
        BSt[e] = B_S[i * 16 + m];
        cb[e] = bu[e] + bi_[e];
    }
    if (e < 64) {
        float sc = 0.f, sd = 0.f;
        for (int m = 0; m < 16; m++) {
            sc += bu[e * 16 + m] + bi_[e * 16 + m];
            sd += bi_[e * 16 + m];
        }
        db[e] = sd;
        eb[e] = sc * (1.0f / 16.0f) - sd;
    }
}

// ---------------------------------------------------------------------------
// kT: coalesced x pass -> xq[b][fo][i][fi]; fa/phi0. Pitch-65 LDS (2-way max).
// ---------------------------------------------------------------------------
__global__ __launch_bounds__(256, 4)
void kT(const float* __restrict__ x, const float* __restrict__ W_A,
        const float* __restrict__ B_A, const float* __restrict__ eb,
        float* __restrict__ xq, float* __restrict__ fa, float* __restrict__ phi)
{
    __shared__ float Xs[2 * 64 * 65];
    const int t = threadIdx.x;
    const int blk = blockIdx.x;

    const float4* x4 = (const float4*)x;
#pragma unroll
    for (int s = 0; s < 8; s++) { // stage 2 batch rows, 1KB/instr coalesced
        int p = s * 256 + t;
        float4 v = x4[(size_t)blk * 2048 + p];
        int b = p >> 10, i = (p >> 4) & 63, fo = p & 15;
        float* row = &Xs[(b * 64 + i) * 65 + fo * 4];
        row[0] = v.x; row[1] = v.y; row[2] = v.z; row[3] = v.w;
    }
    __syncthreads();

    const int lane = t & 63, w = t >> 6;
#pragma unroll
    for (int s = 0; s < 8; s++) { // xq: lane=i, coalesced 1KB writes
        int idx = s * 4 + w;
        int b = idx >> 4, fo = idx & 15;
        const float* row = &Xs[(b * 64 + lane) * 65 + fo * 4];
        ((float4*)xq)[((size_t)(blk * 2 + b) * 16 + fo) * 64 + lane] =
            make_float4(row[0], row[1], row[2], row[3]);
    }

    { // fa/phi: pair p=(b,i), half h sums 32 f's
        int p = t >> 1, h = t & 1;
        int b = p >> 6, i = p & 63;
        const float* row = &Xs[(b * 64 + i) * 65 + h * 32];
        const float* wa = W_A + i * 64 + h * 32;
        float v = 0.f;
#pragma unroll
        for (int j = 0; j < 32; j++) v += row[j] * wa[j];
        v += __shfl_xor(v, 1);
        if (h == 0) {
            float ae = v * 0.125f + B_A[i];
            float fv = 1.0f / (1.0f + expf(-ae));
            size_t o = (size_t)(blk * 2 + b) * 64 + i;
            fa[o] = fv;
            phi[o] = fv * eb[i];
        }
    }
}

// ---------------------------------------------------------------------------
// kA (MFMA bf16x3): tF[b][i][h] = (x[b][i][:] @ W_F1[i]) * 0.125, f32-accurate
// via hi/lo bf16 split, 3 MFMA products, f32 accumulate.
// grid (64 b-tiles, 64 i), 256 thr (4 waves). Wave w owns rows w*16..w*16+15.
// LDS pitch 72 bf16 (rows 16B-aligned, near-uniform bank spread on b128 reads).
// ---------------------------------------------------------------------------
__global__ __launch_bounds__(256, 4)
void kA(const float* __restrict__ x, const float* __restrict__ W_F1,
        float* __restrict__ tF)
{
    __shared__ unsigned short Ah[64][72], Al[64][72]; // A[b][f] hi/lo
    __shared__ unsigned short Bh[64][72], Bl[64][72]; // B^T[h][f] hi/lo
    const int i = blockIdx.y;
    const int b0 = blockIdx.x * 64;
    const int t = threadIdx.x;
    const int bl = t >> 2, q = t & 3;

    { // stage X rows -> Ah/Al (row-major, 8B vector writes)
        const float* src = x + ((size_t)(b0 + bl) * IC + i) * DIM + q * 4;
#pragma unroll
        for (int j4 = 0; j4 < 4; j4++) {
            float4 v = *(const float4*)(src + j4 * 16);
            int f = q * 4 + j4 * 16;
            float vv[4] = {v.x, v.y, v.z, v.w};
            ushort4 h4, l4;
            unsigned short hh;
            hh = f2bf(vv[0]); h4.x = hh; l4.x = f2bf(vv[0] - bf2f(hh));
            hh = f2bf(vv[1]); h4.y = hh; l4.y = f2bf(vv[1] - bf2f(hh));
            hh = f2bf(vv[2]); h4.z = hh; l4.z = f2bf(vv[2] - bf2f(hh));
            hh = f2bf(vv[3]); h4.w = hh; l4.w = f2bf(vv[3] - bf2f(hh));
            *(ushort4*)&Ah[bl][f] = h4;
            *(ushort4*)&Al[bl][f] = l4;
        }
        // stage W rows f=bl, transpose into Bh/Bl[h][f]
        const float* wsrc = W_F1 + ((size_t)i * DIM + bl) * DIM + q * 4;
#pragma unroll
        for (int j4 = 0; j4 < 4; j4++) {
            float4 v = *(const float4*)(wsrc + j4 * 16);
            int h0 = q * 4 + j4 * 16;
            float vv[4] = {v.x, v.y, v.z, v.w};
#pragma unroll
            for (int c = 0; c < 4; c++) {
                unsigned short hh = f2bf(vv[c]);
                Bh[h0 + c][bl] = hh;
                Bl[h0 + c][bl] = f2bf(vv[c] - bf2f(hh));
            }
        }
    }
    __syncthreads();

    const int w = t >> 6, lane = t & 63;
    const int fm = lane & 15, fq = lane >> 4;
    const int r0 = w * 16;
    f32x4 acc[4];
#pragma unroll
    for (int nt = 0; nt < 4; nt++) {
        acc[nt][0] = 0.f; acc[nt][1] = 0.f; acc[nt][2] = 0.f; acc[nt][3] = 0.f;
    }

#pragma unroll
    for (int ks = 0; ks < 2; ks++) {
        const int kk = ks * 32 + fq * 8;
        bf16x8 ah = *(const bf16x8*)&Ah[r0 + fm][kk];
        bf16x8 al = *(const bf16x8*)&Al[r0 + fm][kk];
#pragma unroll
        for (int nt = 0; nt < 4; nt++) {
            bf16x8 bh = *(const bf16x8*)&Bh[nt * 16 + fm][kk];
            bf16x8 bl2 = *(const bf16x8*)&Bl[nt * 16 + fm][kk];
            acc[nt] = __builtin_amdgcn_mfma_f32_16x16x32_bf16(ah, bh, acc[nt], 0, 0, 0);
            acc[nt] = __builtin_amdgcn_mfma_f32_16x16x32_bf16(ah, bl2, acc[nt], 0, 0, 0);
            acc[nt] = __builtin_amdgcn_mfma_f32_16x16x32_bf16(al, bh, acc[nt], 0, 0, 0);
        }
    }

    // C/D layout: col = lane&15, row = (lane>>4)*4 + reg
#pragma unroll
    for (int nt = 0; nt < 4; nt++)
#pragma unroll
        for (int j = 0; j < 4; j++) {
            int row = r0 + fq * 4 + j;
            int col = nt * 16 + fm;
            tF[((size_t)(b0 + row) * IC + i) * DIM + col] = acc[nt][j] * 0.125f;
        }
}

// ---------------------------------------------------------------------------
// kS: s[b][h] = sum_i phi[b][i] * tF[b][i][h].  1024 blocks, wave per b.
// (iteration-0 only; later iterations fused into kC)
// ---------------------------------------------------------------------------
__global__ __launch_bounds__(256, 4)
void kS(const float* __restrict__ phi, const float* __restrict__ tF,
        float* __restrict__ s)
{
    __shared__ float ph[4 * 64];
    const int t = threadIdx.x;
    const int b0 = blockIdx.x * 4;
    ph[t] = phi[(size_t)b0 * 64 + t];
    __syncthreads();

    const int w = t >> 6, lane = t & 63;
    const int ig = lane >> 4, hq = lane & 15;
    const int b = b0 + w;
    const float4* tf4 = (const float4*)(tF + ((size_t)b * 64 + ig * 16) * 64) + hq;
    float4 a = make_float4(0.f, 0.f, 0.f, 0.f);
#pragma unroll
    for (int k = 0; k < 16; k++) {
        float p = ph[w * 64 + ig * 16 + k];
        float4 v = tf4[k * 16];
        a.x += p * v.x; a.y += p * v.y; a.z += p * v.z; a.w += p * v.w;
    }
#pragma unroll
    for (int k = 16; k <= 32; k <<= 1) {
        a.x += __shfl_xor(a.x, k); a.y += __shfl_xor(a.y, k);
        a.z += __shfl_xor(a.z, k); a.w += __shfl_xor(a.w, k);
    }
    if (ig == 0)
        ((float4*)(s + (size_t)b * 64))[hq] = a;
}

// ---------------------------------------------------------------------------
// kXG: per (b-tile 64, m): TWO chained 64x64x64 GEMMs out of LDS (WG12 fold).
//  GEMM1: x_out = s @ W_F2t[:,m,:] + B_F2[m]  -> (last: write out, exit)
//  LN in-register; xhat = xnorm @ WG12[m] + B_G2[m]
// ---------------------------------------------------------------------------
__global__ __launch_bounds__(256, 4)
void kXG(const float* __restrict__ s, const float* __restrict__ WF2t,
         const float* __restrict__ B_F2, const float* __restrict__ WG12,
         const float* __restrict__ B_G2,
         const float* __restrict__ gam, const float* __restrict__ bet,
         float* __restrict__ xhat, float* __restrict__ out, const int last)
{
    __shared__ float A[64][68];  // sT -> xnT  (A[k][b])
    __shared__ float Wb[64][68]; // W panel [k][col]
    const int b0 = blockIdx.x * 64;
    const int m = blockIdx.y;
    const int t = threadIdx.x;
    const int bl = t >> 2, q = t & 3;
    const int tr = t >> 4, tc = t & 15;

    { // stage sT + W_F2t panel
        const float* src = s + (size_t)(b0 + bl) * DIM + q * 4;
#pragma unroll
        for (int j4 = 0; j4 < 4; j4++) {
            float4 v = *(const float4*)(src + j4 * 16);
            int f = q * 4 + j4 * 16;
            A[f + 0][bl] = v.x; A[f + 1][bl] = v.y;
            A[f + 2][bl] = v.z; A[f + 3][bl] = v.w;
        }
        const float* wsrc = WF2t + ((size_t)bl * OC + m) * DIM + q * 4;
#pragma unroll
        for (int j4 = 0; j4 < 4; j4++)
            *(float4*)&Wb[bl][q * 4 + j4 * 16] = *(const float4*)(wsrc + j4 * 16);
    }
    __syncthreads();

    float acc[4][4];
#pragma unroll
    for (int r = 0; r < 4; r++)
#pragma unroll
        for (int c = 0; c < 4; c++) acc[r][c] = 0.f;
#pragma unroll 8
    for (int k = 0; k < 64; k++) {
        float4 a = *(const float4*)&A[k][tr * 4];
        float4 w = *(const float4*)&Wb[k][tc * 4];
        float ar[4] = {a.x, a.y, a.z, a.w};
#pragma unroll
        for (int r = 0; r < 4; r++) {
            acc[r][0] += ar[r] * w.x; acc[r][1] += ar[r] * w.y;
            acc[r][2] += ar[r] * w.z; acc[r][3] += ar[r] * w.w;
        }
    }
    {
        float4 bf = *(const float4*)&B_F2[m * DIM + tc * 4];
#pragma unroll
        for (int r = 0; r < 4; r++) {
            acc[r][0] += bf.x; acc[r][1] += bf.y;
            acc[r][2] += bf.z; acc[r][3] += bf.w;
        }
    }
    if (last) {
#pragma unroll
        for (int r = 0; r < 4; r++)
            *(float4*)&out[((size_t)(b0 + tr * 4 + r) * OC + m) * DIM + tc * 4] =
                make_float4(acc[r][0], acc[r][1], acc[r][2], acc[r][3]);
        return;
    }
    { // LayerNorm rows (row = b, spread over 16 lanes sharing tr)
        float4 gv = *(const float4*)&gam[tc * 4];
        float4 bv = *(const float4*)&bet[tc * 4];
#pragma unroll
        for (int r = 0; r < 4; r++) {
            float sum = acc[r][0] + acc[r][1] + acc[r][2] + acc[r][3];
            float sq = acc[r][0] * acc[r][0] + acc[r][1] * acc[r][1] +
                       acc[r][2] * acc[r][2] + acc[r][3] * acc[r][3];
#pragma unroll
            for (int k = 1; k <= 8; k <<= 1) {
                sum += __shfl_xor(sum, k);
                sq  += __shfl_xor(sq, k);
            }
            float mu = sum * (1.0f / 64.0f);
            float var = sq * (1.0f / 64.0f) - mu * mu;
            float rs = 1.0f / sqrtf(var + 1e-5f);
            acc[r][0] = (acc[r][0] - mu) * rs * gv.x + bv.x;
            acc[r][1] = (acc[r][1] - mu) * rs * gv.y + bv.y;
            acc[r][2] = (acc[r][2] - mu) * rs * gv.z + bv.z;
            acc[r][3] = (acc[r][3] - mu) * rs * gv.w + bv.w;
        }
    }
    __syncthreads(); // GEMM1 reads of A/Wb complete
    { // A <- xnorm^T ; Wb <- WG12[m]
#pragma unroll
        for (int r = 0; r < 4; r++)
#pragma unroll
            for (int c = 0; c < 4; c++)
                A[tc * 4 + c][tr * 4 + r] = acc[r][c];
        const float* wsrc = WG12 + ((size_t)m * DIM + bl) * DIM + q * 4;
#pragma unroll
        for (int j4 = 0; j4 < 4; j4++)
            *(float4*)&Wb[bl][q * 4 + j4 * 16] = *(const float4*)(wsrc + j4 * 16);
    }
    __syncthreads();

    float xh[4][4];
    {
        float4 bg = *(const float4*)&B_G2[m * DIM + tc * 4];
#pragma unroll
        for (int r = 0; r < 4; r++) {
            xh[r][0] = bg.x; xh[r][1] = bg.y; xh[r][2] = bg.z; xh[r][3] = bg.w;
        }
    }
#pragma unroll 8
    for (int k = 0; k < 64; k++) {
        float4 a = *(const float4*)&A[k][tr * 4];
        float4 w = *(const float4*)&Wb[k][tc * 4];
        float ar[4] = {a.x, a.y, a.z, a.w};
#pragma unroll
        for (int r = 0; r < 4; r++) {
            xh[r][0] += ar[r] * w.x; xh[r][1] += ar[r] * w.y;
            xh[r][2] += ar[r] * w.z; xh[r][3] += ar[r] * w.w;
        }
    }
#pragma unroll
    for (int r = 0; r < 4; r++)
        *(float4*)&xhat[((size_t)(b0 + tr * 4 + r) * OC + m) * DIM + tc * 4] =
            make_float4(xh[r][0], xh[r][1], xh[r][2], xh[r][3]);
}

// ---------------------------------------------------------------------------
// kC: consistency + softmax + phi + NEXT-ITER s (fused kS). 4 b/block, 1024
// blocks. phi kept local -> LDS; s computed with the kS wave-per-b pattern.
// ---------------------------------------------------------------------------
__global__ __launch_bounds__(256, 4)
void kC(const float* __restrict__ xq, const float* __restrict__ xhat,
        const float* __restrict__ WSt2, const float* __restrict__ BSt,
        const float* __restrict__ cb, const float* __restrict__ db,
        const float* __restrict__ fa, const float* __restrict__ tF,
        float* __restrict__ s)
{
    __shared__ float buf[4 * 64 * 17]; // xhat view (4096) -> cons view (g*64+i)*17+m
    __shared__ float phs[4][64];
    const int b0 = blockIdx.x * 4;
    const int t = threadIdx.x;
    const int w = t >> 6, lane = t & 63;

    { // stage xhat[b0..b0+4): 4096 floats
        const float4* src = (const float4*)(xhat + (size_t)b0 * OC * DIM);
        float4* dst = (float4*)buf;
#pragma unroll
        for (int j = 0; j < 4; j++) dst[t + j * 256] = src[t + j * 256];
    }
    __syncthreads();

    float acc[4][4];
#pragma unroll
    for (int k = 0; k < 4; k++) {
        float bs = BSt[(w * 4 + k) * IC + lane];
#pragma unroll
        for (int g = 0; g < 4; g++) acc[g][k] = bs;
    }

    const float4* xq4 = (const float4*)xq;
    for (int fc = 0; fc < 64; fc += 8) {
        const int fo = fc >> 2;
        float wreg[4][8];
#pragma unroll
        for (int k = 0; k < 4; k++) {
            int m = w * 4 + k;
#pragma unroll
            for (int q2 = 0; q2 < 2; q2++) {
                float4 v = *(const float4*)&WSt2[(((size_t)m * 16 + fo + q2) * IC + lane) * 4];
                wreg[k][q2 * 4 + 0] = v.x; wreg[k][q2 * 4 + 1] = v.y;
                wreg[k][q2 * 4 + 2] = v.z; wreg[k][q2 * 4 + 3] = v.w;
            }
        }
#pragma unroll
        for (int g = 0; g < 4; g++) {
            float xr[8];
#pragma unroll
            for (int q2 = 0; q2 < 2; q2++) { // coalesced 1KB/instr
                float4 v = xq4[((size_t)(b0 + g) * 16 + fo + q2) * 64 + lane];
                xr[q2 * 4 + 0] = v.x; xr[q2 * 4 + 1] = v.y;
                xr[q2 * 4 + 2] = v.z; xr[q2 * 4 + 3] = v.w;
            }
#pragma unroll
            for (int k = 0; k < 4; k++) {
                int m = w * 4 + k;
                const float* hp = &buf[(g * OC + m) * DIM + fc];
                float hr[8];
#pragma unroll
                for (int q2 = 0; q2 < 2; q2++) { // same-addr broadcast reads
                    float4 v = *(const float4*)(hp + q2 * 4);
                    hr[q2 * 4 + 0] = v.x; hr[q2 * 4 + 1] = v.y;
                    hr[q2 * 4 + 2] = v.z; hr[q2 * 4 + 3] = v.w;
                }
#pragma unroll
                for (int ff = 0; ff < 8; ff++)
                    acc[g][k] += xr[ff] * hr[ff] * wreg[k][ff];
            }
        }
    }
    __syncthreads(); // all xhat reads done before overwrite
#pragma unroll
    for (int g = 0; g < 4; g++)
#pragma unroll
        for (int k = 0; k < 4; k++)
            buf[(g * IC + lane) * 17 + w * 4 + k] = acc[g][k];
    __syncthreads();

    { // softmax over m + phi -> LDS (256 (g,i) pairs, one per thread)
        int g = t >> 6, i = t & 63;
        const float* row = &buf[(g * IC + i) * 17];
        float v[16], mx = -1e30f;
#pragma unroll
        for (int m = 0; m < OC; m++) { v[m] = row[m]; mx = fmaxf(mx, v[m]); }
        float sum = 0.f;
#pragma unroll
        for (int m = 0; m < OC; m++) { v[m] = expf(v[m] - mx); sum += v[m]; }
        float inv = 1.0f / sum;
        float a2 = 0.f;
#pragma unroll
        for (int m = 0; m < OC; m++) a2 += v[m] * inv * cb[i * OC + m];
        phs[g][i] = fa[(size_t)(b0 + g) * IC + i] * (a2 - db[i]);
    }
    __syncthreads();

    { // fused kS: s[b] = sum_i phi[b][i]*tF[b][i][:], wave per b
        const int ig = lane >> 4, hq = lane & 15;
        const int b = b0 + w;
        const float4* tf4 = (const float4*)(tF + ((size_t)b * 64 + ig * 16) * 64) + hq;
        float4 a = make_float4(0.f, 0.f, 0.f, 0.f);
#pragma unroll
        for (int k = 0; k < 16; k++) {
            float p = phs[w][ig * 16 + k];
            float4 v = tf4[k * 16];
            a.x += p * v.x; a.y += p * v.y; a.z += p * v.z; a.w += p * v.w;
        }
#pragma unroll
        for (int k = 16; k <= 32; k <<= 1) {
            a.x += __shfl_xor(a.x, k); a.y += __shfl_xor(a.y, k);
            a.z += __shfl_xor(a.z, k); a.w += __shfl_xor(a.w, k);
        }
        if (ig == 0)
            ((float4*)(s + (size_t)b * 64))[hq] = a;
    }
}

// ---------------------------------------------------------------------------
extern "C" void kernel_launch(void* const* d_in, const int* in_sizes, int n_in,
                              void* d_out, int out_size, void* d_ws, size_t ws_size,
                              hipStream_t stream)
{
    const float* x    = (const float*)d_in[0];
    const float* W_A  = (const float*)d_in[1];
    const float* B_A  = (const float*)d_in[2];
    const float* W_F1 = (const float*)d_in[3];
    const float* W_F2 = (const float*)d_in[4];
    const float* B_F2 = (const float*)d_in[5];
    const float* W_G1 = (const float*)d_in[6];
    const float* W_G2 = (const float*)d_in[7];
    const float* B_G2 = (const float*)d_in[8];
    const float* gam  = (const float*)d_in[9];
    const float* bet  = (const float*)d_in[10];
    const float* W_S  = (const float*)d_in[11];
    const float* B_S  = (const float*)d_in[12];
    const float* bu   = (const float*)d_in[13];
    const float* bi_  = (const float*)d_in[14];

    float* ws   = (float*)d_ws;
    float* tF   = ws;                          // 16777216
    float* xq   = tF + 16777216;               // 16777216
    float* fa   = xq + 16777216;               // 262144
    float* phi  = fa + 262144;                 // 262144
    float* s    = phi + 262144;                // 262144
    float* xhat = s + 262144;                  // 4194304
    float* WF2t = xhat + 4194304;              // 65536
    float* WSt2 = WF2t + 65536;                // 65536
    float* WG12 = WSt2 + 65536;                // 65536
    float* BSt  = WG12 + 65536;                // 1024
    float* cb   = BSt + 1024;                  // 1024
    float* db   = cb + 1024;                   // 64
    float* eb   = db + 64;                     // 64
    float* out  = (float*)d_out;

    kSetup<<<256, 256, 0, stream>>>(W_F2, W_S, B_S, bu, bi_, W_G1, W_G2,
                                    WF2t, WSt2, WG12, BSt, cb, db, eb);
    kT<<<2048, 256, 0, stream>>>(x, W_A, B_A, eb, xq, fa, phi);
    kA<<<dim3(64, 64), 256, 0, stream>>>(x, W_F1, tF);
    kS<<<1024, 256, 0, stream>>>(phi, tF, s);
    for (int it = 0; it < 3; ++it) {
        kXG<<<dim3(64, 16), 256, 0, stream>>>(s, WF2t, B_F2, WG12, B_G2,
                                              gam, bet, xhat, out, it == 2 ? 1 : 0);
        if (it < 2)
            kC<<<1024, 256, 0, stream>>>(xq, xhat, WSt2, BSt, cb, db, fa, tF, s);
    }
}

// Round 8
// 285.184 us; speedup vs baseline: 1.6350x; 1.0791x over previous
//
#include <hip/hip_runtime.h>
#include <math.h>

#define IC 64
#define OC 16
#define DIM 64

typedef __attribute__((ext_vector_type(8))) short bf16x8;
typedef __attribute__((ext_vector_type(4))) float f32x4;

__device__ __forceinline__ unsigned short f2bf(float f) { // RNE float->bf16
    unsigned int b = __float_as_uint(f);
    b += 0x7fffu + ((b >> 16) & 1u);
    return (unsigned short)(b >> 16);
}
__device__ __forceinline__ float bf2f(unsigned short h) {
    return __uint_as_float(((unsigned int)h) << 16);
}

// ---------------------------------------------------------------------------
// kSetup: weight transposes + beta folding + WG12 fold + bf16 hi/lo splits.
//  WSt2[m][fo][i][fi] = W_S[i][m][fo*4+fi]   (lane-i coalesced float4)
//  W1h/W1l[m][d][h] = split(W_F2[m][h][d])           (B^T panel for kXG GEMM1)
//  W2h/W2l[m][f][d] = split(sum_h W_G1[d][h]W_G2[m][h][f])  (B^T for GEMM2)
//  BSt[m][i] = B_S[i][m]; cb[i][m]=bu+bi; db[i]=sum_m bi; eb[i]=sum_m cb/16-db
// ---------------------------------------------------------------------------
__global__ void kSetup(const float* __restrict__ W_F2, const float* __restrict__ W_S,
                       const float* __restrict__ B_S, const float* __restrict__ bu,
                       const float* __restrict__ bi_, const float* __restrict__ W_G1,
                       const float* __restrict__ W_G2,
                       float* __restrict__ WSt2,
                       unsigned short* __restrict__ W1h, unsigned short* __restrict__ W1l,
                       unsigned short* __restrict__ W2h, unsigned short* __restrict__ W2l,
                       float* __restrict__ BSt, float* __restrict__ cb,
                       float* __restrict__ db, float* __restrict__ eb)
{
    int e = blockIdx.x * 256 + threadIdx.x; // 0..65535
    { // W1: B^T of W_F2 panel, bf16 hi/lo
        int h = e >> 10, m = (e >> 6) & 15, d = e & 63;
        float v = W_F2[((size_t)m * 64 + h) * 64 + d];
        unsigned short hh = f2bf(v);
        size_t o = ((size_t)m * 64 + d) * 64 + h;
        W1h[o] = hh; W1l[o] = f2bf(v - bf2f(hh));
    }
    {
        int m = e >> 12, fo = (e >> 8) & 15, i = (e >> 2) & 63, fi = e & 3;
        WSt2[e] = W_S[((size_t)i * 16 + m) * 64 + fo * 4 + fi];
    }
    { // WG12[m][d][f] computed locally, stored transposed as W2[m][f][d]
        int m = e >> 12, d = (e >> 6) & 63, f = e & 63;
        const float* g1 = W_G1 + d * 64;
        const float* g2 = W_G2 + (size_t)m * 4096 + f;
        float a = 0.f;
#pragma unroll 8
        for (int h = 0; h < 64; h++) a += g1[h] * g2[h * 64];
        unsigned short hh = f2bf(a);
        size_t o = ((size_t)m * 64 + f) * 64 + d;
        W2h[o] = hh; W2l[o] = f2bf(a - bf2f(hh));
    }
    if (e < 1024) {
        int m = e >> 6, i = e & 63;
        BSt[e] = B_S[i * 16 + m];
        cb[e] = bu[e] + bi_[e];
    }
    if (e < 64) {
        float sc = 0.f, sd = 0.f;
        for (int m = 0; m < 16; m++) {
            sc += bu[e * 16 + m] + bi_[e * 16 + m];
            sd += bi_[e * 16 + m];
        }
        db[e] = sd;
        eb[e] = sc * (1.0f / 16.0f) - sd;
    }
}

// ---------------------------------------------------------------------------
// kT: coalesced x pass -> xq[b][fo][i][fi]; fa/phi0. Pitch-65 LDS (2-way max).
// ---------------------------------------------------------------------------
__global__ __launch_bounds__(256, 4)
void kT(const float* __restrict__ x, const float* __restrict__ W_A,
        const float* __restrict__ B_A, const float* __restrict__ eb,
        float* __restrict__ xq, float* __restrict__ fa, float* __restrict__ phi)
{
    __shared__ float Xs[2 * 64 * 65];
    const int t = threadIdx.x;
    const int blk = blockIdx.x;

    const float4* x4 = (const float4*)x;
#pragma unroll
    for (int s = 0; s < 8; s++) { // stage 2 batch rows, 1KB/instr coalesced
        int p = s * 256 + t;
        float4 v = x4[(size_t)blk * 2048 + p];
        int b = p >> 10, i = (p >> 4) & 63, fo = p & 15;
        float* row = &Xs[(b * 64 + i) * 65 + fo * 4];
        row[0] = v.x; row[1] = v.y; row[2] = v.z; row[3] = v.w;
    }
    __syncthreads();

    const int lane = t & 63, w = t >> 6;
#pragma unroll
    for (int s = 0; s < 8; s++) { // xq: lane=i, coalesced 1KB writes
        int idx = s * 4 + w;
        int b = idx >> 4, fo = idx & 15;
        const float* row = &Xs[(b * 64 + lane) * 65 + fo * 4];
        ((float4*)xq)[((size_t)(blk * 2 + b) * 16 + fo) * 64 + lane] =
            make_float4(row[0], row[1], row[2], row[3]);
    }

    { // fa/phi: pair p=(b,i), half h sums 32 f's
        int p = t >> 1, h = t & 1;
        int b = p >> 6, i = p & 63;
        const float* row = &Xs[(b * 64 + i) * 65 + h * 32];
        const float* wa = W_A + i * 64 + h * 32;
        float v = 0.f;
#pragma unroll
        for (int j = 0; j < 32; j++) v += row[j] * wa[j];
        v += __shfl_xor(v, 1);
        if (h == 0) {
            float ae = v * 0.125f + B_A[i];
            float fv = 1.0f / (1.0f + expf(-ae));
            size_t o = (size_t)(blk * 2 + b) * 64 + i;
            fa[o] = fv;
            phi[o] = fv * eb[i];
        }
    }
}

// ---------------------------------------------------------------------------
// kA (MFMA bf16x3): tF[b][i][h] = (x[b][i][:] @ W_F1[i]) * 0.125.
// ---------------------------------------------------------------------------
__global__ __launch_bounds__(256, 4)
void kA(const float* __restrict__ x, const float* __restrict__ W_F1,
        float* __restrict__ tF)
{
    __shared__ unsigned short Ah[64][72], Al[64][72]; // A[b][f] hi/lo
    __shared__ unsigned short Bh[64][72], Bl[64][72]; // B^T[h][f] hi/lo
    const int i = blockIdx.y;
    const int b0 = blockIdx.x * 64;
    const int t = threadIdx.x;
    const int bl = t >> 2, q = t & 3;

    { // stage X rows -> Ah/Al
        const float* src = x + ((size_t)(b0 + bl) * IC + i) * DIM + q * 4;
#pragma unroll
        for (int j4 = 0; j4 < 4; j4++) {
            float4 v = *(const float4*)(src + j4 * 16);
            int f = q * 4 + j4 * 16;
            float vv[4] = {v.x, v.y, v.z, v.w};
            ushort4 h4, l4;
            unsigned short hh;
            hh = f2bf(vv[0]); h4.x = hh; l4.x = f2bf(vv[0] - bf2f(hh));
            hh = f2bf(vv[1]); h4.y = hh; l4.y = f2bf(vv[1] - bf2f(hh));
            hh = f2bf(vv[2]); h4.z = hh; l4.z = f2bf(vv[2] - bf2f(hh));
            hh = f2bf(vv[3]); h4.w = hh; l4.w = f2bf(vv[3] - bf2f(hh));
            *(ushort4*)&Ah[bl][f] = h4;
            *(ushort4*)&Al[bl][f] = l4;
        }
        const float* wsrc = W_F1 + ((size_t)i * DIM + bl) * DIM + q * 4;
#pragma unroll
        for (int j4 = 0; j4 < 4; j4++) {
            float4 v = *(const float4*)(wsrc + j4 * 16);
            int h0 = q * 4 + j4 * 16;
            float vv[4] = {v.x, v.y, v.z, v.w};
#pragma unroll
            for (int c = 0; c < 4; c++) {
                unsigned short hh = f2bf(vv[c]);
                Bh[h0 + c][bl] = hh;
                Bl[h0 + c][bl] = f2bf(vv[c] - bf2f(hh));
            }
        }
    }
    __syncthreads();

    const int w = t >> 6, lane = t & 63;
    const int fm = lane & 15, fq = lane >> 4;
    const int r0 = w * 16;
    f32x4 acc[4];
#pragma unroll
    for (int nt = 0; nt < 4; nt++) {
        acc[nt][0] = 0.f; acc[nt][1] = 0.f; acc[nt][2] = 0.f; acc[nt][3] = 0.f;
    }

#pragma unroll
    for (int ks = 0; ks < 2; ks++) {
        const int kk = ks * 32 + fq * 8;
        bf16x8 ah = *(const bf16x8*)&Ah[r0 + fm][kk];
        bf16x8 al = *(const bf16x8*)&Al[r0 + fm][kk];
#pragma unroll
        for (int nt = 0; nt < 4; nt++) {
            bf16x8 bh = *(const bf16x8*)&Bh[nt * 16 + fm][kk];
            bf16x8 bl2 = *(const bf16x8*)&Bl[nt * 16 + fm][kk];
            acc[nt] = __builtin_amdgcn_mfma_f32_16x16x32_bf16(ah, bh, acc[nt], 0, 0, 0);
            acc[nt] = __builtin_amdgcn_mfma_f32_16x16x32_bf16(ah, bl2, acc[nt], 0, 0, 0);
            acc[nt] = __builtin_amdgcn_mfma_f32_16x16x32_bf16(al, bh, acc[nt], 0, 0, 0);
        }
    }

#pragma unroll
    for (int nt = 0; nt < 4; nt++)
#pragma unroll
        for (int j = 0; j < 4; j++) {
            int row = r0 + fq * 4 + j;
            int col = nt * 16 + fm;
            tF[((size_t)(b0 + row) * IC + i) * DIM + col] = acc[nt][j] * 0.125f;
        }
}

// ---------------------------------------------------------------------------
// kS: s[b][h] = sum_i phi[b][i] * tF[b][i][h].  1024 blocks, wave per b.
// (iteration-0 only; later iterations fused into kC)
// ---------------------------------------------------------------------------
__global__ __launch_bounds__(256, 4)
void kS(const float* __restrict__ phi, const float* __restrict__ tF,
        float* __restrict__ s)
{
    __shared__ float ph[4 * 64];
    const int t = threadIdx.x;
    const int b0 = blockIdx.x * 4;
    ph[t] = phi[(size_t)b0 * 64 + t];
    __syncthreads();

    const int w = t >> 6, lane = t & 63;
    const int ig = lane >> 4, hq = lane & 15;
    const int b = b0 + w;
    const float4* tf4 = (const float4*)(tF + ((size_t)b * 64 + ig * 16) * 64) + hq;
    float4 a = make_float4(0.f, 0.f, 0.f, 0.f);
#pragma unroll
    for (int k = 0; k < 16; k++) {
        float p = ph[w * 64 + ig * 16 + k];
        float4 v = tf4[k * 16];
        a.x += p * v.x; a.y += p * v.y; a.z += p * v.z; a.w += p * v.w;
    }
#pragma unroll
    for (int k = 16; k <= 32; k <<= 1) {
        a.x += __shfl_xor(a.x, k); a.y += __shfl_xor(a.y, k);
        a.z += __shfl_xor(a.z, k); a.w += __shfl_xor(a.w, k);
    }
    if (ig == 0)
        ((float4*)(s + (size_t)b * 64))[hq] = a;
}

// ---------------------------------------------------------------------------
// kXG (MFMA bf16x3): per (b-tile 64, m): two chained GEMMs.
//  GEMM1: x_out = s @ W_F2[m] + B_F2[m]  (A=s split on the fly, B=W1 panel)
//  (last: write out, exit)  LN in-register (quad shfl), xnorm->LDS bf16 split
//  GEMM2: xhat = xnorm @ WG12[m] + B_G2[m]  (B=W2 panel)
// LDS: A(hi/lo) + B(hi/lo), both reused across the two GEMMs. 36.9 KB.
// ---------------------------------------------------------------------------
__global__ __launch_bounds__(256, 4)
void kXG(const float* __restrict__ s,
         const unsigned short* __restrict__ W1h, const unsigned short* __restrict__ W1l,
         const float* __restrict__ B_F2,
         const unsigned short* __restrict__ W2h, const unsigned short* __restrict__ W2l,
         const float* __restrict__ B_G2,
         const float* __restrict__ gam, const float* __restrict__ bet,
         float* __restrict__ xhat, float* __restrict__ out, const int last)
{
    __shared__ unsigned short Ah[64][72], Al[64][72]; // s then xnorm (hi/lo)
    __shared__ unsigned short Bh[64][72], Bl[64][72]; // W1^T then W2^T panels
    const int b0 = blockIdx.x * 64;
    const int m = blockIdx.y;
    const int t = threadIdx.x;
    const int bl = t >> 2, q = t & 3;

    { // stage s rows -> Ah/Al (split), W1 panel -> Bh/Bl (copy)
        const float* src = s + (size_t)(b0 + bl) * DIM + q * 16;
#pragma unroll
        for (int j4 = 0; j4 < 4; j4++) {
            float4 v = ((const float4*)src)[j4];
            int f = q * 16 + j4 * 4;
            float vv[4] = {v.x, v.y, v.z, v.w};
            ushort4 h4, l4;
            unsigned short hh;
            hh = f2bf(vv[0]); h4.x = hh; l4.x = f2bf(vv[0] - bf2f(hh));
            hh = f2bf(vv[1]); h4.y = hh; l4.y = f2bf(vv[1] - bf2f(hh));
            hh = f2bf(vv[2]); h4.z = hh; l4.z = f2bf(vv[2] - bf2f(hh));
            hh = f2bf(vv[3]); h4.w = hh; l4.w = f2bf(vv[3] - bf2f(hh));
            *(ushort4*)&Ah[bl][f] = h4;
            *(ushort4*)&Al[bl][f] = l4;
        }
        const size_t wo = ((size_t)m * 64 + bl) * 64 + q * 16;
#pragma unroll
        for (int part = 0; part < 2; part++) {
            *(uint4*)&Bh[bl][q * 16 + part * 8] = *(const uint4*)(W1h + wo + part * 8);
            *(uint4*)&Bl[bl][q * 16 + part * 8] = *(const uint4*)(W1l + wo + part * 8);
        }
    }
    __syncthreads();

    const int w = t >> 6, lane = t & 63;
    const int fm = lane & 15, fq = lane >> 4;
    const int r0 = w * 16;
    f32x4 acc[4];
#pragma unroll
    for (int nt = 0; nt < 4; nt++) {
        acc[nt][0] = 0.f; acc[nt][1] = 0.f; acc[nt][2] = 0.f; acc[nt][3] = 0.f;
    }
#pragma unroll
    for (int ks = 0; ks < 2; ks++) {
        const int kk = ks * 32 + fq * 8;
        bf16x8 ah = *(const bf16x8*)&Ah[r0 + fm][kk];
        bf16x8 al = *(const bf16x8*)&Al[r0 + fm][kk];
#pragma unroll
        for (int nt = 0; nt < 4; nt++) {
            bf16x8 bh = *(const bf16x8*)&Bh[nt * 16 + fm][kk];
            bf16x8 bl2 = *(const bf16x8*)&Bl[nt * 16 + fm][kk];
            acc[nt] = __builtin_amdgcn_mfma_f32_16x16x32_bf16(ah, bh, acc[nt], 0, 0, 0);
            acc[nt] = __builtin_amdgcn_mfma_f32_16x16x32_bf16(ah, bl2, acc[nt], 0, 0, 0);
            acc[nt] = __builtin_amdgcn_mfma_f32_16x16x32_bf16(al, bh, acc[nt], 0, 0, 0);
        }
    }
#pragma unroll
    for (int nt = 0; nt < 4; nt++) { // + B_F2[m]
        float bf = B_F2[m * DIM + nt * 16 + fm];
#pragma unroll
        for (int j = 0; j < 4; j++) acc[nt][j] += bf;
    }

    if (last) { // final x_out
#pragma unroll
        for (int nt = 0; nt < 4; nt++)
#pragma unroll
            for (int j = 0; j < 4; j++) {
                int row = r0 + fq * 4 + j;
                out[((size_t)(b0 + row) * OC + m) * DIM + nt * 16 + fm] = acc[nt][j];
            }
        return;
    }

    { // LayerNorm: row = b = r0+fq*4+j lives across 16 fm-lanes x 4 regs
        float g4[4], b4[4];
#pragma unroll
        for (int nt = 0; nt < 4; nt++) {
            g4[nt] = gam[nt * 16 + fm];
            b4[nt] = bet[nt * 16 + fm];
        }
#pragma unroll
        for (int j = 0; j < 4; j++) {
            float sum = acc[0][j] + acc[1][j] + acc[2][j] + acc[3][j];
            float sq = acc[0][j] * acc[0][j] + acc[1][j] * acc[1][j] +
                       acc[2][j] * acc[2][j] + acc[3][j] * acc[3][j];
#pragma unroll
            for (int k = 1; k <= 8; k <<= 1) {
                sum += __shfl_xor(sum, k);
                sq  += __shfl_xor(sq, k);
            }
            float mu = sum * (1.0f / 64.0f);
            float var = sq * (1.0f / 64.0f) - mu * mu;
            float rs = 1.0f / sqrtf(var + 1e-5f);
#pragma unroll
            for (int nt = 0; nt < 4; nt++)
                acc[nt][j] = (acc[nt][j] - mu) * rs * g4[nt] + b4[nt];
        }
    }
    __syncthreads(); // GEMM1 LDS reads complete before overwrite

    { // A <- xnorm (split, C-layout scatter); B <- W2 panel
#pragma unroll
        for (int nt = 0; nt < 4; nt++)
#pragma unroll
            for (int j = 0; j < 4; j++) {
                float v = acc[nt][j];
                unsigned short hh = f2bf(v);
                int row = r0 + fq * 4 + j, col = nt * 16 + fm;
                Ah[row][col] = hh;
                Al[row][col] = f2bf(v - bf2f(hh));
            }
        const size_t wo = ((size_t)m * 64 + bl) * 64 + q * 16;
#pragma unroll
        for (int part = 0; part < 2; part++) {
            *(uint4*)&Bh[bl][q * 16 + part * 8] = *(const uint4*)(W2h + wo + part * 8);
            *(uint4*)&Bl[bl][q * 16 + part * 8] = *(const uint4*)(W2l + wo + part * 8);
        }
    }
    __syncthreads();

    f32x4 xh[4];
#pragma unroll
    for (int nt = 0; nt < 4; nt++) {
        float bg = B_G2[m * DIM + nt * 16 + fm];
        xh[nt][0] = bg; xh[nt][1] = bg; xh[nt][2] = bg; xh[nt][3] = bg;
    }
#pragma unroll
    for (int ks = 0; ks < 2; ks++) {
        const int kk = ks * 32 + fq * 8;
        bf16x8 ah = *(const bf16x8*)&Ah[r0 + fm][kk];
        bf16x8 al = *(const bf16x8*)&Al[r0 + fm][kk];
#pragma unroll
        for (int nt = 0; nt < 4; nt++) {
            bf16x8 bh = *(const bf16x8*)&Bh[nt * 16 + fm][kk];
            bf16x8 bl2 = *(const bf16x8*)&Bl[nt * 16 + fm][kk];
            xh[nt] = __builtin_amdgcn_mfma_f32_16x16x32_bf16(ah, bh, xh[nt], 0, 0, 0);
            xh[nt] = __builtin_amdgcn_mfma_f32_16x16x32_bf16(ah, bl2, xh[nt], 0, 0, 0);
            xh[nt] = __builtin_amdgcn_mfma_f32_16x16x32_bf16(al, bh, xh[nt], 0, 0, 0);
        }
    }
#pragma unroll
    for (int nt = 0; nt < 4; nt++)
#pragma unroll
        for (int j = 0; j < 4; j++) {
            int row = r0 + fq * 4 + j;
            xhat[((size_t)(b0 + row) * OC + m) * DIM + nt * 16 + fm] = xh[nt][j];
        }
}

// ---------------------------------------------------------------------------
// kC: consistency + softmax + phi + NEXT-ITER s (fused kS). 4 b/block, 1024
// blocks. phi kept local -> LDS; s computed with the kS wave-per-b pattern.
// ---------------------------------------------------------------------------
__global__ __launch_bounds__(256, 4)
void kC(const float* __restrict__ xq, const float* __restrict__ xhat,
        const float* __restrict__ WSt2, const float* __restrict__ BSt,
        const float* __restrict__ cb, const float* __restrict__ db,
        const float* __restrict__ fa, const float* __restrict__ tF,
        float* __restrict__ s)
{
    __shared__ float buf[4 * 64 * 17]; // xhat view (4096) -> cons view (g*64+i)*17+m
    __shared__ float phs[4][64];
    const int b0 = blockIdx.x * 4;
    const int t = threadIdx.x;
    const int w = t >> 6, lane = t & 63;

    { // stage xhat[b0..b0+4): 4096 floats
        const float4* src = (const float4*)(xhat + (size_t)b0 * OC * DIM);
        float4* dst = (float4*)buf;
#pragma unroll
        for (int j = 0; j < 4; j++) dst[t + j * 256] = src[t + j * 256];
    }
    __syncthreads();

    float acc[4][4];
#pragma unroll
    for (int k = 0; k < 4; k++) {
        float bs = BSt[(w * 4 + k) * IC + lane];
#pragma unroll
        for (int g = 0; g < 4; g++) acc[g][k] = bs;
    }

    const float4* xq4 = (const float4*)xq;
    for (int fc = 0; fc < 64; fc += 8) {
        const int fo = fc >> 2;
        float wreg[4][8];
#pragma unroll
        for (int k = 0; k < 4; k++) {
            int m = w * 4 + k;
#pragma unroll
            for (int q2 = 0; q2 < 2; q2++) {
                float4 v = *(const float4*)&WSt2[(((size_t)m * 16 + fo + q2) * IC + lane) * 4];
                wreg[k][q2 * 4 + 0] = v.x; wreg[k][q2 * 4 + 1] = v.y;
                wreg[k][q2 * 4 + 2] = v.z; wreg[k][q2 * 4 + 3] = v.w;
            }
        }
#pragma unroll
        for (int g = 0; g < 4; g++) {
            float xr[8];
#pragma unroll
            for (int q2 = 0; q2 < 2; q2++) { // coalesced 1KB/instr
                float4 v = xq4[((size_t)(b0 + g) * 16 + fo + q2) * 64 + lane];
                xr[q2 * 4 + 0] = v.x; xr[q2 * 4 + 1] = v.y;
                xr[q2 * 4 + 2] = v.z; xr[q2 * 4 + 3] = v.w;
            }
#pragma unroll
            for (int k = 0; k < 4; k++) {
                int m = w * 4 + k;
                const float* hp = &buf[(g * OC + m) * DIM + fc];
                float hr[8];
#pragma unroll
                for (int q2 = 0; q2 < 2; q2++) { // same-addr broadcast reads
                    float4 v = *(const float4*)(hp + q2 * 4);
                    hr[q2 * 4 + 0] = v.x; hr[q2 * 4 + 1] = v.y;
                    hr[q2 * 4 + 2] = v.z; hr[q2 * 4 + 3] = v.w;
                }
#pragma unroll
                for (int ff = 0; ff < 8; ff++)
                    acc[g][k] += xr[ff] * hr[ff] * wreg[k][ff];
            }
        }
    }
    __syncthreads(); // all xhat reads done before overwrite
#pragma unroll
    for (int g = 0; g < 4; g++)
#pragma unroll
        for (int k = 0; k < 4; k++)
            buf[(g * IC + lane) * 17 + w * 4 + k] = acc[g][k];
    __syncthreads();

    { // softmax over m + phi -> LDS (256 (g,i) pairs, one per thread)
        int g = t >> 6, i = t & 63;
        const float* row = &buf[(g * IC + i) * 17];
        float v[16], mx = -1e30f;
#pragma unroll
        for (int m = 0; m < OC; m++) { v[m] = row[m]; mx = fmaxf(mx, v[m]); }
        float sum = 0.f;
#pragma unroll
        for (int m = 0; m < OC; m++) { v[m] = expf(v[m] - mx); sum += v[m]; }
        float inv = 1.0f / sum;
        float a2 = 0.f;
#pragma unroll
        for (int m = 0; m < OC; m++) a2 += v[m] * inv * cb[i * OC + m];
        phs[g][i] = fa[(size_t)(b0 + g) * IC + i] * (a2 - db[i]);
    }
    __syncthreads();

    { // fused kS: s[b] = sum_i phi[b][i]*tF[b][i][:], wave per b
        const int ig = lane >> 4, hq = lane & 15;
        const int b = b0 + w;
        const float4* tf4 = (const float4*)(tF + ((size_t)b * 64 + ig * 16) * 64) + hq;
        float4 a = make_float4(0.f, 0.f, 0.f, 0.f);
#pragma unroll
        for (int k = 0; k < 16; k++) {
            float p = phs[w][ig * 16 + k];
            float4 v = tf4[k * 16];
            a.x += p * v.x; a.y += p * v.y; a.z += p * v.z; a.w += p * v.w;
        }
#pragma unroll
        for (int k = 16; k <= 32; k <<= 1) {
            a.x += __shfl_xor(a.x, k); a.y += __shfl_xor(a.y, k);
            a.z += __shfl_xor(a.z, k); a.w += __shfl_xor(a.w, k);
        }
        if (ig == 0)
            ((float4*)(s + (size_t)b * 64))[hq] = a;
    }
}

// ---------------------------------------------------------------------------
extern "C" void kernel_launch(void* const* d_in, const int* in_sizes, int n_in,
                              void* d_out, int out_size, void* d_ws, size_t ws_size,
                              hipStream_t stream)
{
    const float* x    = (const float*)d_in[0];
    const float* W_A  = (const float*)d_in[1];
    const float* B_A  = (const float*)d_in[2];
    const float* W_F1 = (const float*)d_in[3];
    const float* W_F2 = (const float*)d_in[4];
    const float* B_F2 = (const float*)d_in[5];
    const float* W_G1 = (const float*)d_in[6];
    const float* W_G2 = (const float*)d_in[7];
    const float* B_G2 = (const float*)d_in[8];
    const float* gam  = (const float*)d_in[9];
    const float* bet  = (const float*)d_in[10];
    const float* W_S  = (const float*)d_in[11];
    const float* B_S  = (const float*)d_in[12];
    const float* bu   = (const float*)d_in[13];
    const float* bi_  = (const float*)d_in[14];

    float* ws   = (float*)d_ws;
    float* tF   = ws;                          // 16777216
    float* xq   = tF + 16777216;               // 16777216
    float* fa   = xq + 16777216;               // 262144
    float* phi  = fa + 262144;                 // 262144
    float* s    = phi + 262144;                // 262144
    float* xhat = s + 262144;                  // 4194304
    float* WSt2 = xhat + 4194304;              // 65536
    unsigned short* W1h = (unsigned short*)(WSt2 + 65536); // 65536 ushort = 32768 f
    unsigned short* W1l = W1h + 65536;
    unsigned short* W2h = W1l + 65536;
    unsigned short* W2l = W2h + 65536;
    float* BSt  = (float*)(W2l + 65536);       // 1024
    float* cb   = BSt + 1024;                  // 1024
    float* db   = cb + 1024;                   // 64
    float* eb   = db + 64;                     // 64
    float* out  = (float*)d_out;

    kSetup<<<256, 256, 0, stream>>>(W_F2, W_S, B_S, bu, bi_, W_G1, W_G2,
                                    WSt2, W1h, W1l, W2h, W2l, BSt, cb, db, eb);
    kT<<<2048, 256, 0, stream>>>(x, W_A, B_A, eb, xq, fa, phi);
    kA<<<dim3(64, 64), 256, 0, stream>>>(x, W_F1, tF);
    kS<<<1024, 256, 0, stream>>>(phi, tF, s);
    for (int it = 0; it < 3; ++it) {
        kXG<<<dim3(64, 16), 256, 0, stream>>>(s, W1h, W1l, B_F2, W2h, W2l, B_G2,
                                              gam, bet, xhat, out, it == 2 ? 1 : 0);
        if (it < 2)
            kC<<<1024, 256, 0, stream>>>(xq, xhat, WSt2, BSt, cb, db, fa, tF, s);
    }
}